// Round 2
// baseline (69579.065 us; speedup 1.0000x reference)
//
#include <hip/hip_runtime.h>
#include <hip/hip_cooperative_groups.h>
#include <math.h>

namespace cg = cooperative_groups;

#define LSEQ 512
#define BATCH 64
#define HID 1024
#define NCH 8
#define GSZ 4112

typedef __bf16 bf16x8 __attribute__((ext_vector_type(8)));
typedef float f32x4 __attribute__((ext_vector_type(4)));

__device__ __forceinline__ ushort f2b(float f) {
  union { float f; unsigned u; } v; v.f = f;
  unsigned u = v.u;
  unsigned r = (u + 0x7FFFu + ((u >> 16) & 1u)) >> 16;  // RNE
  return (ushort)r;
}

__device__ __forceinline__ float sigmoidf(float x) { return 1.f / (1.f + expf(-x)); }

// ---- transpose + cast: W (K x N) f32 -> WT (N x K) bf16 ----
__global__ __launch_bounds__(256) void k_transpose_cast(
    const float* __restrict__ W, ushort* __restrict__ WT, int K, int N) {
  __shared__ float tile[32][33];
  int n0 = blockIdx.x * 32, k0 = blockIdx.y * 32;
  int tx = threadIdx.x & 31, ty = threadIdx.x >> 5;
  #pragma unroll
  for (int i = ty; i < 32; i += 8) {
    int n = n0 + tx;
    tile[i][tx] = (n < N) ? W[(size_t)(k0 + i) * N + n] : 0.f;
  }
  __syncthreads();
  #pragma unroll
  for (int i = ty; i < 32; i += 8) {
    int n = n0 + i;
    if (n < N) WT[(size_t)n * K + k0 + tx] = f2b(tile[tx][i]);
  }
}

// ---- f32 -> bf16 cast (vectorized x4) ----
__global__ void k_cast4(const float4* __restrict__ in, ushort* __restrict__ out, int count4) {
  int stride = gridDim.x * blockDim.x;
  for (int i = blockIdx.x * blockDim.x + threadIdx.x; i < count4; i += stride) {
    float4 v = in[i];
    ushort4 o;
    o.x = f2b(v.x); o.y = f2b(v.y); o.z = f2b(v.z); o.w = f2b(v.w);
    *reinterpret_cast<ushort4*>(out + (size_t)i * 4) = o;
  }
}

__global__ void k_init_state(const float* __restrict__ h0l, const float* __restrict__ c0l,
                             ushort* __restrict__ hb, float* __restrict__ c, int count) {
  int i = blockIdx.x * blockDim.x + threadIdx.x;
  if (i < count) { hb[i] = f2b(h0l[i]); c[i] = c0l[i]; }
}

// C[M x N](f32) = A[M x K](bf16) @ BT[N x K](bf16)^T + bias[N]
// 64x64 tile per block, 4 waves, MFMA 16x16x32 bf16. Used for t_in chunks.
__global__ __launch_bounds__(256) void k_gemm(
    const ushort* __restrict__ A, const ushort* __restrict__ BT,
    const float* __restrict__ bias, float* __restrict__ C, int K, int N) {
  int col0 = blockIdx.x * 64;
  int row0 = blockIdx.y * 64;
  int lane = threadIdx.x & 63;
  int w = threadIdx.x >> 6;
  int l15 = lane & 15;
  int koff = (lane >> 4) * 8;
  const ushort* Ap = A + (size_t)(row0 + w * 16 + l15) * K + koff;
  const ushort* Bp[4];
  int cols[4];
  #pragma unroll
  for (int cg_ = 0; cg_ < 4; ++cg_) {
    int c_ = col0 + cg_ * 16 + l15;
    cols[cg_] = c_;
    int cc = c_ < N ? c_ : N - 1;
    Bp[cg_] = BT + (size_t)cc * K + koff;
  }
  f32x4 acc[4] = {};
  #pragma unroll 2
  for (int kk = 0; kk < K; kk += 32) {
    bf16x8 a = *reinterpret_cast<const bf16x8*>(Ap + kk);
    #pragma unroll
    for (int cg_ = 0; cg_ < 4; ++cg_) {
      bf16x8 b = *reinterpret_cast<const bf16x8*>(Bp[cg_] + kk);
      acc[cg_] = __builtin_amdgcn_mfma_f32_16x16x32_bf16(a, b, acc[cg_], 0, 0, 0);
    }
  }
  int crow = row0 + w * 16 + (lane >> 4) * 4;
  #pragma unroll
  for (int cg_ = 0; cg_ < 4; ++cg_) {
    int c_ = cols[cg_];
    if (c_ >= N) continue;
    float bv = bias[c_];
    #pragma unroll
    for (int i = 0; i < 4; ++i)
      C[(size_t)(crow + i) * N + c_] = acc[cg_][i] + bv;
  }
}

// ---- persistent cooperative scan over one chunk of timesteps ----
// 256 blocks (1/CU). Block owns 4 hidden cols -> 16 gate cols + 16 shared
// softmax cols. Whh slice lives in LDS in MFMA B-fragment order for the
// whole chunk. c-state lives in one register per thread. One grid.sync/step.
__global__ __launch_bounds__(256, 1) void k_scan(
    const ushort* __restrict__ WhhT,  // [GSZ][HID] bf16
    const float* __restrict__ bhh,    // [GSZ]
    const float* __restrict__ tin,    // [nsteps][BATCH][GSZ] f32
    ushort* __restrict__ h,           // [BATCH][HID] bf16 (in/out)
    float* __restrict__ cws,          // [BATCH][HID] f32 (in/out)
    float* __restrict__ out_hs,       // outs[l] + t0 offset
    float* __restrict__ out_hs2,      // output dup (layer 1) or null
    float* __restrict__ dfs,          // + (l*512+t0)*64
    float* __restrict__ dins,
    float* __restrict__ hT, float* __restrict__ cT,  // last chunk only
    int nsteps) {
  __shared__ ushort bfrag[2 * 32 * 64 * 8];  // 64KB: [cg][kb][lane][8]
  __shared__ float gbuf[32][68];             // gates: [col][batch], padded

  const int tid = threadIdx.x;
  const int blk = blockIdx.x;
  const int j0 = blk * 4;
  const int lane = tid & 63;
  const int w = tid >> 6;
  const int l15 = lane & 15;
  const int koff = (lane >> 4) * 8;

  // ---- stage Whh B-fragments into LDS (once per chunk) ----
  for (int idx = tid; idx < 2 * 32 * 64; idx += 256) {
    int cgi = idx >> 11;          // 0 = softmax cols, 1 = own gate cols
    int kb = (idx >> 6) & 31;
    int ln = idx & 63;
    int c = ln & 15;
    int gcol = (cgi == 0) ? c : (16 + (c >> 2) * 1024 + j0 + (c & 3));
    int k = kb * 32 + (ln >> 4) * 8;
    *reinterpret_cast<uint4*>(&bfrag[(size_t)idx * 8]) =
        *reinterpret_cast<const uint4*>(&WhhT[(size_t)gcol * HID + k]);
  }

  // per-thread cell state: thread -> (batch cb, local hidden cj)
  const int cb = tid >> 2;
  const int cj = tid & 3;
  const int jglob = j0 + cj;
  const int r = jglob >> 7;  // chunk index 0..7
  float creg = cws[cb * HID + jglob];

  // hoisted per-lane epilogue constants
  const int col = l15;
  const int gcol1 = 16 + (col >> 2) * 1024 + j0 + (col & 3);
  const float bv0 = bhh[col];
  const float bv1 = bhh[gcol1];
  const int crow = w * 16 + (lane >> 4) * 4;

  cg::grid_group grid = cg::this_grid();
  __syncthreads();

  for (int tt = 0; tt < nsteps; ++tt) {
    // ---- GEMM: 32 cols x 64 batch, K=1024 ----
    f32x4 acc0 = {}, acc1 = {};
    const ushort* hp = h + (size_t)(w * 16 + l15) * HID + koff;
    #pragma unroll 8
    for (int kb = 0; kb < 32; ++kb) {
      bf16x8 a = *reinterpret_cast<const bf16x8*>(hp + kb * 32);
      bf16x8 b0 = *reinterpret_cast<const bf16x8*>(&bfrag[(size_t)(kb * 64 + lane) * 8]);
      bf16x8 b1 = *reinterpret_cast<const bf16x8*>(&bfrag[(size_t)((32 + kb) * 64 + lane) * 8]);
      acc0 = __builtin_amdgcn_mfma_f32_16x16x32_bf16(a, b0, acc0, 0, 0, 0);
      acc1 = __builtin_amdgcn_mfma_f32_16x16x32_bf16(a, b1, acc1, 0, 0, 0);
    }
    // epilogue: + bhh + t_in -> LDS gate buffer
    const float* tb = tin + ((size_t)tt * BATCH + crow) * GSZ;
    #pragma unroll
    for (int i = 0; i < 4; ++i) {
      gbuf[col][crow + i] = acc0[i] + bv0 + tb[(size_t)i * GSZ + col];
      gbuf[16 + col][crow + i] = acc1[i] + bv1 + tb[(size_t)i * GSZ + gcol1];
    }
    __syncthreads();

    // ---- fused cell update ----
    float sm0[NCH], sm1[NCH];
    float m1 = -1e30f, m2 = -1e30f;
    #pragma unroll
    for (int i = 0; i < NCH; ++i) {
      sm0[i] = gbuf[i][cb];
      sm1[i] = gbuf[NCH + i][cb];
      m1 = fmaxf(m1, sm0[i]);
      m2 = fmaxf(m2, sm1[i]);
    }
    float s1 = 0.f, s2 = 0.f;
    #pragma unroll
    for (int i = 0; i < NCH; ++i) {
      sm0[i] = expf(sm0[i] - m1); s1 += sm0[i];
      sm1[i] = expf(sm1[i] - m2); s2 += sm1[i];
    }
    float cum1 = 0.f, cum2 = 0.f, sumin = 0.f, sumfg = 0.f;
    float cing[NCH], cfg[NCH];
    #pragma unroll
    for (int i = 0; i < NCH; ++i) {
      cum1 += sm0[i] / s1; cing[i] = 1.f - cum1; sumin += cing[i];
      cum2 += sm1[i] / s2; cfg[i] = cum2; sumfg += cfg[i];
    }
    float go = gbuf[16 + cj][cb];
    float gc = gbuf[16 + 4 + cj][cb];
    float gi = gbuf[16 + 8 + cj][cb];
    float gf = gbuf[16 + 12 + cj][cb];
    float ov = cfg[r] * cing[r];
    float f_ = sigmoidf(gf) * ov + (cfg[r] - ov);
    float i_ = sigmoidf(gi) * ov + (cing[r] - ov);
    float cy = f_ * creg + i_ * tanhf(gc);
    float hy = sigmoidf(go) * tanhf(cy);
    creg = cy;

    h[cb * HID + jglob] = f2b(hy);
    size_t oidx = ((size_t)tt * BATCH + cb) * HID + jglob;
    out_hs[oidx] = hy;
    if (out_hs2) out_hs2[oidx] = hy;
    if (hT && tt == nsteps - 1) {
      hT[cb * HID + jglob] = hy;
      cT[cb * HID + jglob] = cy;
    }
    if (blk == 0 && cj == 0) {
      dfs[tt * BATCH + cb] = 1.f - sumfg * 0.125f;
      dins[tt * BATCH + cb] = sumin * 0.125f;
    }

    __threadfence();
    grid.sync();
  }
  cws[cb * HID + jglob] = creg;
}

extern "C" void kernel_launch(void* const* d_in, const int* in_sizes, int n_in,
                              void* d_out, int out_size, void* d_ws, size_t ws_size,
                              hipStream_t stream) {
  const float* x   = (const float*)d_in[0];
  const float* h0  = (const float*)d_in[1];
  const float* c0  = (const float*)d_in[2];
  const float* Wih = (const float*)d_in[3];
  const float* bih = (const float*)d_in[4];
  const float* Whh = (const float*)d_in[5];
  const float* bhh = (const float*)d_in[6];
  float* out = (float*)d_out;

  const size_t OFF_OUTPUT = 0;                  // (512,64,1024)
  const size_t OFF_HT   = 33554432;             // (2,64,1024)
  const size_t OFF_CT   = OFF_HT + 131072;      // (2,64,8,128)
  const size_t OFF_OUTS = OFF_CT + 131072;      // (2,512,64,1024)
  const size_t OFF_DFS  = OFF_OUTS + 67108864;  // (2,512,64)
  const size_t OFF_DINS = OFF_DFS + 65536;      // (2,512,64)

  uint8_t* ws = (uint8_t*)d_ws;
  size_t off = 0;
  auto alloc = [&](size_t bytes) { size_t p = off; off = (off + bytes + 255) & ~(size_t)255; return p; };
  const size_t wT_sz = (size_t)GSZ * HID * 2;
  size_t o_WihT[2], o_WhhT[2];
  o_WihT[0] = alloc(wT_sz); o_WihT[1] = alloc(wT_sz);
  o_WhhT[0] = alloc(wT_sz); o_WhhT[1] = alloc(wT_sz);
  size_t o_hb = alloc((size_t)BATCH * HID * 2);
  size_t o_c  = alloc((size_t)BATCH * HID * 4);
  size_t fixed = off;
  const size_t unit = (size_t)BATCH * HID * 2 + (size_t)BATCH * GSZ * 4 + 512;
  int TC = 128;
  while (TC > 1 && fixed + (size_t)TC * unit > ws_size) TC >>= 1;
  size_t o_prevb = alloc((size_t)TC * BATCH * HID * 2);
  size_t o_tin   = alloc((size_t)TC * BATCH * GSZ * 4);

  ushort* hb    = (ushort*)(ws + o_hb);
  float*  cst   = (float*)(ws + o_c);
  ushort* prevb = (ushort*)(ws + o_prevb);
  float*  tin   = (float*)(ws + o_tin);

  dim3 tgrid((GSZ + 31) / 32, HID / 32);
  for (int l = 0; l < 2; ++l) {
    k_transpose_cast<<<tgrid, 256, 0, stream>>>(Wih + (size_t)l * HID * GSZ,
                                                (ushort*)(ws + o_WihT[l]), HID, GSZ);
    k_transpose_cast<<<tgrid, 256, 0, stream>>>(Whh + (size_t)l * HID * GSZ,
                                                (ushort*)(ws + o_WhhT[l]), HID, GSZ);
  }

  const int NB = (GSZ + 63) / 64;
  for (int l = 0; l < 2; ++l) {
    const float* prev = (l == 0) ? x : (out + OFF_OUTS);  // layer-0 hs in outs[0]
    const ushort* WihT = (const ushort*)(ws + o_WihT[l]);

    k_init_state<<<256, 256, 0, stream>>>(h0 + (size_t)l * BATCH * HID,
                                          c0 + (size_t)l * BATCH * HID,
                                          hb, cst, BATCH * HID);

    for (int t0 = 0; t0 < LSEQ; t0 += TC) {
      int nsteps = (LSEQ - t0 < TC) ? (LSEQ - t0) : TC;

      int count4 = nsteps * BATCH * HID / 4;
      int cblocks = (count4 + 255) / 256; if (cblocks > 2048) cblocks = 2048;
      k_cast4<<<cblocks, 256, 0, stream>>>(
          (const float4*)(prev + (size_t)t0 * BATCH * HID), prevb, count4);

      k_gemm<<<dim3(NB, nsteps), 256, 0, stream>>>(prevb, WihT, bih + (size_t)l * GSZ,
                                                   tin, HID, GSZ);

      bool last = (t0 + nsteps == LSEQ);
      const ushort* WhhT_p = (const ushort*)(ws + o_WhhT[l]);
      const float* bhh_p = bhh + (size_t)l * GSZ;
      const float* tin_p = tin;
      ushort* h_p = hb;
      float* c_p = cst;
      float* ohs  = out + OFF_OUTS + ((size_t)l * LSEQ + t0) * BATCH * HID;
      float* ohs2 = (l == 1) ? (out + OFF_OUTPUT + (size_t)t0 * BATCH * HID) : nullptr;
      float* dfsp  = out + OFF_DFS  + ((size_t)l * LSEQ + t0) * BATCH;
      float* dinsp = out + OFF_DINS + ((size_t)l * LSEQ + t0) * BATCH;
      float* hTp = last ? (out + OFF_HT + (size_t)l * BATCH * HID) : nullptr;
      float* cTp = last ? (out + OFF_CT + (size_t)l * BATCH * HID) : nullptr;
      int nsteps_v = nsteps;

      void* args[] = {&WhhT_p, &bhh_p, &tin_p, &h_p, &c_p, &ohs, &ohs2,
                      &dfsp, &dinsp, &hTp, &cTp, &nsteps_v};
      hipLaunchCooperativeKernel((const void*)k_scan, dim3(256), dim3(256),
                                 args, 0, stream);
    }
  }
}

// Round 4
// 31249.991 us; speedup vs baseline: 2.2265x; 2.2265x over previous
//
#include <hip/hip_runtime.h>
#include <math.h>

#define LSEQ 512
#define BATCH 64
#define HID 1024
#define NCH 8
#define GSZ 4112
#define NBLK 64

typedef __bf16 bf16x8 __attribute__((ext_vector_type(8)));
typedef float f32x4 __attribute__((ext_vector_type(4)));
typedef unsigned u32x4 __attribute__((ext_vector_type(4)));

__device__ __forceinline__ ushort f2b(float f) {
  union { float f; unsigned u; } v; v.f = f;
  unsigned u = v.u;
  unsigned r = (u + 0x7FFFu + ((u >> 16) & 1u)) >> 16;  // RNE
  return (ushort)r;
}

__device__ __forceinline__ float sigmoidf(float x) { return 1.f / (1.f + expf(-x)); }

// ---- transpose + cast: W (K x N) f32 -> WT (N x K) bf16 ----
__global__ __launch_bounds__(256) void k_transpose_cast(
    const float* __restrict__ W, ushort* __restrict__ WT, int K, int N) {
  __shared__ float tile[32][33];
  int n0 = blockIdx.x * 32, k0 = blockIdx.y * 32;
  int tx = threadIdx.x & 31, ty = threadIdx.x >> 5;
  #pragma unroll
  for (int i = ty; i < 32; i += 8) {
    int n = n0 + tx;
    tile[i][tx] = (n < N) ? W[(size_t)(k0 + i) * N + n] : 0.f;
  }
  __syncthreads();
  #pragma unroll
  for (int i = ty; i < 32; i += 8) {
    int n = n0 + i;
    if (n < N) WT[(size_t)n * K + k0 + tx] = f2b(tile[tx][i]);
  }
}

// ---- f32 -> bf16 cast (vectorized x4) ----
__global__ void k_cast4(const float4* __restrict__ in, ushort* __restrict__ out, int count4) {
  int stride = gridDim.x * blockDim.x;
  for (int i = blockIdx.x * blockDim.x + threadIdx.x; i < count4; i += stride) {
    float4 v = in[i];
    ushort4 o;
    o.x = f2b(v.x); o.y = f2b(v.y); o.z = f2b(v.z); o.w = f2b(v.w);
    *reinterpret_cast<ushort4*>(out + (size_t)i * 4) = o;
  }
}

__global__ void k_init_state(const float* __restrict__ h0l, const float* __restrict__ c0l,
                             ushort* __restrict__ hb, float* __restrict__ c,
                             unsigned* __restrict__ bar, int count) {
  int i = blockIdx.x * blockDim.x + threadIdx.x;
  if (i < count) { hb[i] = f2b(h0l[i]); c[i] = c0l[i]; }
  if (i == 0) *bar = 0u;
}

// Ct[t][col][batch] (f32) = A[t*64+b][K](bf16) @ BT[col][K](bf16)^T + bias[col]
// Transposed output so the scan kernel reads tin coalesced over batch.
__global__ __launch_bounds__(256) void k_gemm_t(
    const ushort* __restrict__ A, const ushort* __restrict__ BT,
    const float* __restrict__ bias, float* __restrict__ Ct, int K, int N) {
  int col0 = blockIdx.x * 64;
  int t = blockIdx.y;
  int lane = threadIdx.x & 63;
  int w = threadIdx.x >> 6;
  int l15 = lane & 15;
  int koff = (lane >> 4) * 8;
  const ushort* Ap = A + (size_t)(t * 64 + w * 16 + l15) * K + koff;
  const ushort* Bp[4];
  int cols[4];
  #pragma unroll
  for (int cg = 0; cg < 4; ++cg) {
    int c_ = col0 + cg * 16 + l15;
    cols[cg] = c_;
    int cc = c_ < N ? c_ : N - 1;  // clamp reads on partial tile
    Bp[cg] = BT + (size_t)cc * K + koff;
  }
  f32x4 acc[4] = {};
  #pragma unroll 4
  for (int kk = 0; kk < K; kk += 32) {
    bf16x8 a = *reinterpret_cast<const bf16x8*>(Ap + kk);
    #pragma unroll
    for (int cg = 0; cg < 4; ++cg) {
      bf16x8 b = *reinterpret_cast<const bf16x8*>(Bp[cg] + kk);
      acc[cg] = __builtin_amdgcn_mfma_f32_16x16x32_bf16(a, b, acc[cg], 0, 0, 0);
    }
  }
  int crow = w * 16 + (lane >> 4) * 4;  // batch row base
  #pragma unroll
  for (int cg = 0; cg < 4; ++cg) {
    int c_ = cols[cg];
    if (c_ >= N) continue;
    float bv = bias[c_];
    float4 o;
    o.x = acc[cg][0] + bv; o.y = acc[cg][1] + bv;
    o.z = acc[cg][2] + bv; o.w = acc[cg][3] + bv;
    *reinterpret_cast<float4*>(&Ct[((size_t)t * GSZ + c_) * 64 + crow]) = o;
  }
}

// ---- persistent scan: 64 blocks x 1024 threads (16 waves) ----
// Block owns 16 hidden units -> 64 gate cols (4 kinds x 16) + 16 redundant
// softmax cols. h double-buffered in global, exchanged via sc0/sc1 (LLC-
// coherent) ops; barrier = monotone atomic counter (no L2 flush). Whh frags
// read from (stable) per-XCD L2. h staged to LDS (XOR-swizzled) once/step.
// barbase = number of barrier rounds already executed this layer (fixes the
// round-3 deadlock: each chunk performs nsteps-1 barriers, not nsteps).
__global__ __launch_bounds__(1024, 4) void k_scan(
    const ushort* __restrict__ WhhT,  // [GSZ][HID] bf16
    const float* __restrict__ bhh,
    const float* __restrict__ tin,    // [nsteps][GSZ][64] f32 (transposed!)
    ushort* __restrict__ hbuf0, ushort* __restrict__ hbuf1,  // [64][1024] bf16
    float* __restrict__ cws,          // [64][1024] f32
    float* __restrict__ out_hs, float* __restrict__ out_hs2,
    float* __restrict__ dfs, float* __restrict__ dins,
    float* __restrict__ hT, float* __restrict__ cT,
    unsigned* __restrict__ bar, int nsteps, int barbase) {
  __shared__ unsigned hlds[32768];   // 128 KB: h staged, XOR-swizzled
  __shared__ float gbuf[80][65];     // [col][batch]: 0..15 sm, 16+q*16+j own

  const int tid = threadIdx.x;
  const int blk = blockIdx.x;
  const int j0 = blk * 16;
  const int lane = tid & 63;
  const int w = tid >> 6;       // wave 0..15
  const int q = w >> 2;         // gate kind 0..3 (out,cell,in,fg)
  const int bt = w & 3;         // batch tile
  const int l15 = lane & 15;
  const int koff = (lane >> 4) * 8;

  // A-frag LDS addressing (row = batch, XOR swizzle per 8 rows)
  const int arow = bt * 16 + l15;
  const unsigned abase = (unsigned)arow * 2048u + (unsigned)koff * 2u;
  const unsigned aswz = (unsigned)(arow & 7) << 4;

  // B-frag global pointers (L2-resident)
  const int own_gcol = 16 + q * 1024 + j0 + l15;
  const ushort* bp = WhhT + (size_t)own_gcol * HID + koff;
  const ushort* sp = WhhT + (size_t)l15 * HID + koff;  // softmax cols (w<4)
  const float bv  = bhh[own_gcol];
  const float bvs = bhh[l15];
  const int crow = bt * 16 + ((lane >> 4) << 2);  // batch row base in C
  const float* tinb  = tin + (size_t)own_gcol * 64 + crow;
  const float* tinsb = tin + (size_t)l15 * 64 + crow;

  // cell mapping: thread -> (batch cb, local hidden jl)
  const int cb = tid >> 4;
  const int jl = tid & 15;
  const int jglob = j0 + jl;
  const int r = jglob >> 7;
  float creg = cws[cb * HID + jglob];

  for (int tt = 0; tt < nsteps; ++tt) {
    // ---- stage h (coherent LLC read) -> LDS, swizzled ----
    const u32x4* hs = (const u32x4*)((tt & 1) ? hbuf1 : hbuf0);
    u32x4 v0, v1, v2, v3, v4, v5, v6, v7;
#define CLOAD(dst, I) asm volatile("global_load_dwordx4 %0, %1, off sc0 sc1" \
      : "=v"(dst) : "v"(hs + tid + (I)*1024) : "memory")
    CLOAD(v0, 0); CLOAD(v1, 1); CLOAD(v2, 2); CLOAD(v3, 3);
    CLOAD(v4, 4); CLOAD(v5, 5); CLOAD(v6, 6); CLOAD(v7, 7);
#undef CLOAD
    asm volatile("s_waitcnt vmcnt(0)" ::: "memory");
    __builtin_amdgcn_sched_barrier(0);
#define WST(v, I) { unsigned byte_ = (unsigned)(tid + (I)*1024) * 16u; \
    unsigned row_ = byte_ >> 11; \
    *(u32x4*)((char*)hlds + (byte_ ^ ((row_ & 7u) << 4))) = v; }
    WST(v0, 0); WST(v1, 1); WST(v2, 2); WST(v3, 3);
    WST(v4, 4); WST(v5, 5); WST(v6, 6); WST(v7, 7);
#undef WST
    __syncthreads();

    // ---- GEMM: own tile (+ softmax tile for waves 0-3) ----
    float4 ti = *reinterpret_cast<const float4*>(tinb + (size_t)tt * GSZ * 64);
    float4 tis = {0, 0, 0, 0};
    if (w < 4) tis = *reinterpret_cast<const float4*>(tinsb + (size_t)tt * GSZ * 64);

    f32x4 acc = {}, accs = {};
    #pragma unroll 8
    for (int kb = 0; kb < 32; ++kb) {
      bf16x8 a = *reinterpret_cast<const bf16x8*>(
          (const char*)hlds + ((abase + (unsigned)kb * 64u) ^ aswz));
      bf16x8 b = *reinterpret_cast<const bf16x8*>(bp + kb * 32);
      acc = __builtin_amdgcn_mfma_f32_16x16x32_bf16(a, b, acc, 0, 0, 0);
      if (w < 4) {
        bf16x8 b2 = *reinterpret_cast<const bf16x8*>(sp + kb * 32);
        accs = __builtin_amdgcn_mfma_f32_16x16x32_bf16(a, b2, accs, 0, 0, 0);
      }
    }
    {
      float* g0 = &gbuf[16 + q * 16 + l15][crow];
      g0[0] = acc[0] + bv + ti.x; g0[1] = acc[1] + bv + ti.y;
      g0[2] = acc[2] + bv + ti.z; g0[3] = acc[3] + bv + ti.w;
      if (w < 4) {
        float* g1 = &gbuf[l15][crow];
        g1[0] = accs[0] + bvs + tis.x; g1[1] = accs[1] + bvs + tis.y;
        g1[2] = accs[2] + bvs + tis.z; g1[3] = accs[3] + bvs + tis.w;
      }
    }
    __syncthreads();

    // ---- fused cell update ----
    float sm0[NCH], sm1[NCH];
    float m1 = -1e30f, m2 = -1e30f;
    #pragma unroll
    for (int i = 0; i < NCH; ++i) {
      sm0[i] = gbuf[i][cb];
      sm1[i] = gbuf[NCH + i][cb];
      m1 = fmaxf(m1, sm0[i]);
      m2 = fmaxf(m2, sm1[i]);
    }
    float s1 = 0.f, s2 = 0.f;
    #pragma unroll
    for (int i = 0; i < NCH; ++i) {
      sm0[i] = expf(sm0[i] - m1); s1 += sm0[i];
      sm1[i] = expf(sm1[i] - m2); s2 += sm1[i];
    }
    float cum1 = 0.f, cum2 = 0.f, sumin = 0.f, sumfg = 0.f;
    float cing[NCH], cfg[NCH];
    #pragma unroll
    for (int i = 0; i < NCH; ++i) {
      cum1 += sm0[i] / s1; cing[i] = 1.f - cum1; sumin += cing[i];
      cum2 += sm1[i] / s2; cfg[i] = cum2; sumfg += cfg[i];
    }
    float go = gbuf[16 + jl][cb];
    float gc = gbuf[32 + jl][cb];
    float gi = gbuf[48 + jl][cb];
    float gf = gbuf[64 + jl][cb];
    float ov = cfg[r] * cing[r];
    float f_ = sigmoidf(gf) * ov + (cfg[r] - ov);
    float i_ = sigmoidf(gi) * ov + (cing[r] - ov);
    float cy = f_ * creg + i_ * tanhf(gc);
    float hy = sigmoidf(go) * tanhf(cy);
    creg = cy;

    // h store: coherent (write-through to LLC), packed bf16 pairs
    ushort hv = f2b(hy);
    unsigned other = (unsigned)__shfl_xor((int)(unsigned)hv, 1, 64);
    ushort* hw = ((tt & 1) ? hbuf0 : hbuf1) + cb * HID + j0 + jl;
    if ((jl & 1) == 0) {
      unsigned pk = (unsigned)hv | (other << 16);
      asm volatile("global_store_dword %0, %1, off sc0 sc1" :: "v"(hw), "v"(pk) : "memory");
    }

    size_t oidx = ((size_t)tt * BATCH + cb) * HID + jglob;
    out_hs[oidx] = hy;
    if (out_hs2) out_hs2[oidx] = hy;
    if (hT && tt == nsteps - 1) {
      hT[cb * HID + jglob] = hy;
      cT[cb * HID + jglob] = cy;
    }
    if (blk == 0 && jl == 0) {
      dfs[tt * BATCH + cb] = 1.f - sumfg * 0.125f;
      dins[tt * BATCH + cb] = sumin * 0.125f;
    }

    // ---- grid barrier (no cache flush): monotone counter ----
    // Each chunk executes exactly nsteps-1 rounds; cumulative count = barbase.
    if (tt < nsteps - 1) {
      asm volatile("s_waitcnt vmcnt(0)" ::: "memory");  // h stores at LLC
      __syncthreads();
      if (tid == 0) {
        unsigned tgt = (unsigned)(barbase + tt + 1) * NBLK;
        __hip_atomic_fetch_add(bar, 1u, __ATOMIC_RELAXED, __HIP_MEMORY_SCOPE_AGENT);
        while (__hip_atomic_fetch_add(bar, 0u, __ATOMIC_RELAXED,
                                      __HIP_MEMORY_SCOPE_AGENT) < tgt)
          __builtin_amdgcn_s_sleep(2);
      }
      __syncthreads();
    }
  }
  cws[cb * HID + jglob] = creg;
}

extern "C" void kernel_launch(void* const* d_in, const int* in_sizes, int n_in,
                              void* d_out, int out_size, void* d_ws, size_t ws_size,
                              hipStream_t stream) {
  const float* x   = (const float*)d_in[0];
  const float* h0  = (const float*)d_in[1];
  const float* c0  = (const float*)d_in[2];
  const float* Wih = (const float*)d_in[3];
  const float* bih = (const float*)d_in[4];
  const float* Whh = (const float*)d_in[5];
  const float* bhh = (const float*)d_in[6];
  float* out = (float*)d_out;

  const size_t OFF_OUTPUT = 0;                  // (512,64,1024)
  const size_t OFF_HT   = 33554432;             // (2,64,1024)
  const size_t OFF_CT   = OFF_HT + 131072;      // (2,64,8,128)
  const size_t OFF_OUTS = OFF_CT + 131072;      // (2,512,64,1024)
  const size_t OFF_DFS  = OFF_OUTS + 67108864;  // (2,512,64)
  const size_t OFF_DINS = OFF_DFS + 65536;      // (2,512,64)

  uint8_t* ws = (uint8_t*)d_ws;
  size_t off = 0;
  auto alloc = [&](size_t bytes) { size_t p = off; off = (off + bytes + 255) & ~(size_t)255; return p; };
  const size_t wT_sz = (size_t)GSZ * HID * 2;
  size_t o_WihT[2], o_WhhT[2];
  o_WihT[0] = alloc(wT_sz); o_WihT[1] = alloc(wT_sz);
  o_WhhT[0] = alloc(wT_sz); o_WhhT[1] = alloc(wT_sz);
  size_t o_h0b = alloc((size_t)BATCH * HID * 2);
  size_t o_h1b = alloc((size_t)BATCH * HID * 2);
  size_t o_c   = alloc((size_t)BATCH * HID * 4);
  size_t o_bar = alloc(256);
  size_t fixed = off;
  const size_t unit = (size_t)BATCH * HID * 2 + (size_t)BATCH * GSZ * 4 + 512;
  int TC = 128;
  while (TC > 2 && fixed + (size_t)TC * unit > ws_size) TC >>= 1;
  size_t o_prevb = alloc((size_t)TC * BATCH * HID * 2);
  size_t o_tin   = alloc((size_t)TC * BATCH * GSZ * 4);

  ushort* hb0 = (ushort*)(ws + o_h0b);
  ushort* hb1 = (ushort*)(ws + o_h1b);
  float*  cst = (float*)(ws + o_c);
  unsigned* bar = (unsigned*)(ws + o_bar);
  ushort* prevb = (ushort*)(ws + o_prevb);
  float*  tin   = (float*)(ws + o_tin);

  dim3 tgrid((GSZ + 31) / 32, HID / 32);
  for (int l = 0; l < 2; ++l) {
    k_transpose_cast<<<tgrid, 256, 0, stream>>>(Wih + (size_t)l * HID * GSZ,
                                                (ushort*)(ws + o_WihT[l]), HID, GSZ);
    k_transpose_cast<<<tgrid, 256, 0, stream>>>(Whh + (size_t)l * HID * GSZ,
                                                (ushort*)(ws + o_WhhT[l]), HID, GSZ);
  }

  const int NB = (GSZ + 63) / 64;
  for (int l = 0; l < 2; ++l) {
    const float* prev = (l == 0) ? x : (out + OFF_OUTS);  // layer-0 hs in outs[0]
    const ushort* WihT = (const ushort*)(ws + o_WihT[l]);

    k_init_state<<<256, 256, 0, stream>>>(h0 + (size_t)l * BATCH * HID,
                                          c0 + (size_t)l * BATCH * HID,
                                          hb0, cst, bar, BATCH * HID);

    int barbase = 0;  // cumulative barrier rounds this layer
    for (int t0 = 0; t0 < LSEQ; t0 += TC) {
      int nsteps = (LSEQ - t0 < TC) ? (LSEQ - t0) : TC;

      int count4 = nsteps * BATCH * HID / 4;
      int cblocks = (count4 + 255) / 256; if (cblocks > 2048) cblocks = 2048;
      k_cast4<<<cblocks, 256, 0, stream>>>(
          (const float4*)(prev + (size_t)t0 * BATCH * HID), prevb, count4);

      k_gemm_t<<<dim3(NB, nsteps), 256, 0, stream>>>(prevb, WihT,
                                                     bih + (size_t)l * GSZ, tin, HID, GSZ);

      bool last = (t0 + nsteps == LSEQ);
      const ushort* WhhT_p = (const ushort*)(ws + o_WhhT[l]);
      const float* bhh_p = bhh + (size_t)l * GSZ;
      const float* tin_p = tin;
      ushort* h0_p = hb0;
      ushort* h1_p = hb1;
      float* c_p = cst;
      float* ohs  = out + OFF_OUTS + ((size_t)l * LSEQ + t0) * BATCH * HID;
      float* ohs2 = (l == 1) ? (out + OFF_OUTPUT + (size_t)t0 * BATCH * HID) : nullptr;
      float* dfsp  = out + OFF_DFS  + ((size_t)l * LSEQ + t0) * BATCH;
      float* dinsp = out + OFF_DINS + ((size_t)l * LSEQ + t0) * BATCH;
      float* hTp = last ? (out + OFF_HT + (size_t)l * BATCH * HID) : nullptr;
      float* cTp = last ? (out + OFF_CT + (size_t)l * BATCH * HID) : nullptr;
      int nsteps_v = nsteps;
      int barbase_v = barbase;

      void* args[] = {&WhhT_p, &bhh_p, &tin_p, &h0_p, &h1_p, &c_p, &ohs, &ohs2,
                      &dfsp, &dinsp, &hTp, &cTp, &bar, &nsteps_v, &barbase_v};
      hipLaunchCooperativeKernel((const void*)k_scan, dim3(NBLK), dim3(1024),
                                 args, 0, stream);
      barbase += nsteps - 1;
    }
  }
}

// Round 5
// 29374.994 us; speedup vs baseline: 2.3686x; 1.0638x over previous
//
#include <hip/hip_runtime.h>
#include <math.h>

#define LSEQ 512
#define BATCH 64
#define HID 1024
#define NCH 8
#define GSZ 4112
#define NBLK 64

typedef __bf16 bf16x8 __attribute__((ext_vector_type(8)));
typedef float f32x4 __attribute__((ext_vector_type(4)));
typedef unsigned u32x4 __attribute__((ext_vector_type(4)));

__device__ __forceinline__ ushort f2b(float f) {
  union { float f; unsigned u; } v; v.f = f;
  unsigned u = v.u;
  unsigned r = (u + 0x7FFFu + ((u >> 16) & 1u)) >> 16;  // RNE
  return (ushort)r;
}
__device__ __forceinline__ float b2f(ushort h) {
  union { unsigned u; float f; } v; v.u = (unsigned)h << 16; return v.f;
}
__device__ __forceinline__ float sigmoidf(float x) { return 1.f / (1.f + expf(-x)); }

// ---- transpose + cast: W (K x N) f32 -> WT (N x K) bf16 ----
__global__ __launch_bounds__(256) void k_transpose_cast(
    const float* __restrict__ W, ushort* __restrict__ WT, int K, int N) {
  __shared__ float tile[32][33];
  int n0 = blockIdx.x * 32, k0 = blockIdx.y * 32;
  int tx = threadIdx.x & 31, ty = threadIdx.x >> 5;
  #pragma unroll
  for (int i = ty; i < 32; i += 8) {
    int n = n0 + tx;
    tile[i][tx] = (n < N) ? W[(size_t)(k0 + i) * N + n] : 0.f;
  }
  __syncthreads();
  #pragma unroll
  for (int i = ty; i < 32; i += 8) {
    int n = n0 + i;
    if (n < N) WT[(size_t)n * K + k0 + tx] = f2b(tile[tx][i]);
  }
}

// ---- f32 -> bf16 cast (vectorized x4) ----
__global__ void k_cast4(const float4* __restrict__ in, ushort* __restrict__ out, int count4) {
  int stride = gridDim.x * blockDim.x;
  for (int i = blockIdx.x * blockDim.x + threadIdx.x; i < count4; i += stride) {
    float4 v = in[i];
    ushort4 o;
    o.x = f2b(v.x); o.y = f2b(v.y); o.z = f2b(v.z); o.w = f2b(v.w);
    *reinterpret_cast<ushort4*>(out + (size_t)i * 4) = o;
  }
}

__global__ void k_init_state(const float* __restrict__ h0l, const float* __restrict__ c0l,
                             ushort* __restrict__ hb, float* __restrict__ c,
                             unsigned* __restrict__ bar, int count) {
  int i = blockIdx.x * blockDim.x + threadIdx.x;
  if (i < count) { hb[i] = f2b(h0l[i]); c[i] = c0l[i]; }
  if (i == 0) { bar[0] = 0u; bar[64] = 0u; }  // arrival counter + release word
}

// Ct[t][col][batch] (bf16) = A[t*64+b][K](bf16) @ BT[col][K](bf16)^T + bias[col]
// Transposed bf16 output: scan reads tin coalesced over batch, half the bytes.
__global__ __launch_bounds__(256) void k_gemm_t(
    const ushort* __restrict__ A, const ushort* __restrict__ BT,
    const float* __restrict__ bias, ushort* __restrict__ Ct, int K, int N) {
  int col0 = blockIdx.x * 64;
  int t = blockIdx.y;
  int lane = threadIdx.x & 63;
  int w = threadIdx.x >> 6;
  int l15 = lane & 15;
  int koff = (lane >> 4) * 8;
  const ushort* Ap = A + (size_t)(t * 64 + w * 16 + l15) * K + koff;
  const ushort* Bp[4];
  int cols[4];
  #pragma unroll
  for (int cg = 0; cg < 4; ++cg) {
    int c_ = col0 + cg * 16 + l15;
    cols[cg] = c_;
    int cc = c_ < N ? c_ : N - 1;  // clamp reads on partial tile
    Bp[cg] = BT + (size_t)cc * K + koff;
  }
  f32x4 acc[4] = {};
  #pragma unroll 4
  for (int kk = 0; kk < K; kk += 32) {
    bf16x8 a = *reinterpret_cast<const bf16x8*>(Ap + kk);
    #pragma unroll
    for (int cg = 0; cg < 4; ++cg) {
      bf16x8 b = *reinterpret_cast<const bf16x8*>(Bp[cg] + kk);
      acc[cg] = __builtin_amdgcn_mfma_f32_16x16x32_bf16(a, b, acc[cg], 0, 0, 0);
    }
  }
  int crow = w * 16 + (lane >> 4) * 4;  // batch row base
  #pragma unroll
  for (int cg = 0; cg < 4; ++cg) {
    int c_ = cols[cg];
    if (c_ >= N) continue;
    float bv = bias[c_];
    ushort4 o;
    o.x = f2b(acc[cg][0] + bv); o.y = f2b(acc[cg][1] + bv);
    o.z = f2b(acc[cg][2] + bv); o.w = f2b(acc[cg][3] + bv);
    *reinterpret_cast<ushort4*>(&Ct[((size_t)t * GSZ + c_) * 64 + crow]) = o;
  }
}

// ---- persistent scan: 64 blocks x 1024 threads (16 waves) ----
// Block owns 16 hidden units -> 64 gate cols (4 kinds x 16) + 16 redundant
// softmax cols. h double-buffered in global, exchanged via sc0/sc1 (LLC)
// ops; barrier = fetch_add arrival + LOAD-polled release word (no RMW poll,
// no cache flush). Whh frags from per-XCD L2. h staged to LDS once/step.
__global__ __launch_bounds__(1024, 4) void k_scan(
    const ushort* __restrict__ WhhT,  // [GSZ][HID] bf16
    const float* __restrict__ bhh,
    const ushort* __restrict__ tin,   // [nsteps][GSZ][64] bf16 (transposed!)
    ushort* __restrict__ hbuf0, ushort* __restrict__ hbuf1,  // [64][1024] bf16
    float* __restrict__ cws,          // [64][1024] f32
    float* __restrict__ out_hs, float* __restrict__ out_hs2,
    float* __restrict__ dfs, float* __restrict__ dins,
    float* __restrict__ hT, float* __restrict__ cT,
    unsigned* __restrict__ bar, int nsteps, int barbase) {
  __shared__ unsigned hlds[32768];   // 128 KB: h staged, XOR-swizzled
  __shared__ float gbuf[80][68];     // [col][batch]: 0..15 sm, 16+q*16+j own

  const int tid = threadIdx.x;
  const int blk = blockIdx.x;
  const int j0 = blk * 16;
  const int lane = tid & 63;
  const int w = tid >> 6;       // wave 0..15
  const int q = w >> 2;         // gate kind 0..3 (out,cell,in,fg)
  const int bt = w & 3;         // batch tile
  const int l15 = lane & 15;
  const int koff = (lane >> 4) * 8;

  // A-frag LDS addressing (row = batch, XOR swizzle per 8 rows)
  const int arow = bt * 16 + l15;
  const unsigned abase = (unsigned)arow * 2048u + (unsigned)koff * 2u;
  const unsigned aswz = (unsigned)(arow & 7) << 4;

  // B-frag global pointers (L2-resident)
  const int own_gcol = 16 + q * 1024 + j0 + l15;
  const ushort* bp = WhhT + (size_t)own_gcol * HID + koff;
  const ushort* sp = WhhT + (size_t)l15 * HID + koff;  // softmax cols (w<4)
  const float bv  = bhh[own_gcol];
  const float bvs = bhh[l15];
  const int crow = bt * 16 + ((lane >> 4) << 2);  // batch row base in C
  const ushort* tinb  = tin + (size_t)own_gcol * 64 + crow;
  const ushort* tinsb = tin + (size_t)l15 * 64 + crow;

  // cell mapping: thread -> (batch cb, local hidden jl)
  const int cb = tid >> 4;
  const int jl = tid & 15;
  const int jglob = j0 + jl;
  const int r = jglob >> 7;
  float creg = cws[cb * HID + jglob];

  // prefetch tin for step 0
  ushort4 tv = *reinterpret_cast<const ushort4*>(tinb);
  ushort4 tvs = {0, 0, 0, 0};
  if (w < 4) tvs = *reinterpret_cast<const ushort4*>(tinsb);

  for (int tt = 0; tt < nsteps; ++tt) {
    // ---- stage h (coherent LLC read) -> LDS, swizzled ----
    const u32x4* hs = (const u32x4*)((tt & 1) ? hbuf1 : hbuf0);
    u32x4 v0, v1, v2, v3, v4, v5, v6, v7;
#define CLOAD(dst, I) asm volatile("global_load_dwordx4 %0, %1, off sc0 sc1" \
      : "=v"(dst) : "v"(hs + tid + (I)*1024) : "memory")
    CLOAD(v0, 0); CLOAD(v1, 1); CLOAD(v2, 2); CLOAD(v3, 3);
    CLOAD(v4, 4); CLOAD(v5, 5); CLOAD(v6, 6); CLOAD(v7, 7);
#undef CLOAD
    asm volatile("s_waitcnt vmcnt(0)" ::: "memory");
    __builtin_amdgcn_sched_barrier(0);
#define WST(v, I) { unsigned byte_ = (unsigned)(tid + (I)*1024) * 16u; \
    unsigned row_ = byte_ >> 11; \
    *(u32x4*)((char*)hlds + (byte_ ^ ((row_ & 7u) << 4))) = v; }
    WST(v0, 0); WST(v1, 1); WST(v2, 2); WST(v3, 3);
    WST(v4, 4); WST(v5, 5); WST(v6, 6); WST(v7, 7);
#undef WST
    __syncthreads();

    // ---- GEMM: own tile (+ softmax tile for waves 0-3) ----
    f32x4 acc = {}, accs = {};
    #pragma unroll 8
    for (int kb = 0; kb < 32; ++kb) {
      bf16x8 a = *reinterpret_cast<const bf16x8*>(
          (const char*)hlds + ((abase + (unsigned)kb * 64u) ^ aswz));
      bf16x8 b = *reinterpret_cast<const bf16x8*>(bp + kb * 32);
      acc = __builtin_amdgcn_mfma_f32_16x16x32_bf16(a, b, acc, 0, 0, 0);
      if (w < 4) {
        bf16x8 b2 = *reinterpret_cast<const bf16x8*>(sp + kb * 32);
        accs = __builtin_amdgcn_mfma_f32_16x16x32_bf16(a, b2, accs, 0, 0, 0);
      }
    }
    {  // float4 epilogue stores (bank-uniform)
      f32x4 g;
      g[0] = acc[0] + bv + b2f(tv.x); g[1] = acc[1] + bv + b2f(tv.y);
      g[2] = acc[2] + bv + b2f(tv.z); g[3] = acc[3] + bv + b2f(tv.w);
      *reinterpret_cast<f32x4*>(&gbuf[16 + q * 16 + l15][crow]) = g;
      if (w < 4) {
        f32x4 g2;
        g2[0] = accs[0] + bvs + b2f(tvs.x); g2[1] = accs[1] + bvs + b2f(tvs.y);
        g2[2] = accs[2] + bvs + b2f(tvs.z); g2[3] = accs[3] + bvs + b2f(tvs.w);
        *reinterpret_cast<f32x4*>(&gbuf[l15][crow]) = g2;
      }
    }
    // prefetch next step's tin (independent of barrier; hides HBM latency)
    if (tt + 1 < nsteps) {
      tv = *reinterpret_cast<const ushort4*>(tinb + (size_t)(tt + 1) * GSZ * 64);
      if (w < 4) tvs = *reinterpret_cast<const ushort4*>(tinsb + (size_t)(tt + 1) * GSZ * 64);
    }
    __syncthreads();

    // ---- fused cell update ----
    float sm0[NCH], sm1[NCH];
    float m1 = -1e30f, m2 = -1e30f;
    #pragma unroll
    for (int i = 0; i < NCH; ++i) {
      sm0[i] = gbuf[i][cb];
      sm1[i] = gbuf[NCH + i][cb];
      m1 = fmaxf(m1, sm0[i]);
      m2 = fmaxf(m2, sm1[i]);
    }
    float s1 = 0.f, s2 = 0.f;
    #pragma unroll
    for (int i = 0; i < NCH; ++i) {
      sm0[i] = expf(sm0[i] - m1); s1 += sm0[i];
      sm1[i] = expf(sm1[i] - m2); s2 += sm1[i];
    }
    float r1 = 1.f / s1, r2 = 1.f / s2;
    float cum1 = 0.f, cum2 = 0.f, sumin = 0.f, sumfg = 0.f;
    float cing[NCH], cfg[NCH];
    #pragma unroll
    for (int i = 0; i < NCH; ++i) {
      cum1 += sm0[i] * r1; cing[i] = 1.f - cum1; sumin += cing[i];
      cum2 += sm1[i] * r2; cfg[i] = cum2; sumfg += cfg[i];
    }
    float go = gbuf[16 + jl][cb];
    float gc = gbuf[32 + jl][cb];
    float gi = gbuf[48 + jl][cb];
    float gf = gbuf[64 + jl][cb];
    float ov = cfg[r] * cing[r];
    float f_ = sigmoidf(gf) * ov + (cfg[r] - ov);
    float i_ = sigmoidf(gi) * ov + (cing[r] - ov);
    float cy = f_ * creg + i_ * tanhf(gc);
    float hy = sigmoidf(go) * tanhf(cy);
    creg = cy;

    // h store: coherent (write-through to LLC), packed bf16 pairs
    ushort hv = f2b(hy);
    unsigned other = (unsigned)__shfl_xor((int)(unsigned)hv, 1, 64);
    ushort* hw = ((tt & 1) ? hbuf0 : hbuf1) + cb * HID + j0 + jl;
    if ((jl & 1) == 0) {
      unsigned pk = (unsigned)hv | (other << 16);
      asm volatile("global_store_dword %0, %1, off sc0 sc1" :: "v"(hw), "v"(pk) : "memory");
    }

    size_t oidx = ((size_t)tt * BATCH + cb) * HID + jglob;
    out_hs[oidx] = hy;
    if (out_hs2) out_hs2[oidx] = hy;
    if (hT && tt == nsteps - 1) {
      hT[cb * HID + jglob] = hy;
      cT[cb * HID + jglob] = cy;
    }
    if (blk == 0 && jl == 0) {
      dfs[tt * BATCH + cb] = 1.f - sumfg * 0.125f;
      dins[tt * BATCH + cb] = sumin * 0.125f;
    }

    // ---- grid barrier: fetch_add arrival, LOAD-polled release ----
    if (tt < nsteps - 1) {
      asm volatile("s_waitcnt vmcnt(0)" ::: "memory");  // h stores at LLC
      __syncthreads();
      if (tid == 0) {
        unsigned tgt = (unsigned)(barbase + tt + 1) * NBLK;
        unsigned old = __hip_atomic_fetch_add(&bar[0], 1u, __ATOMIC_RELAXED,
                                              __HIP_MEMORY_SCOPE_AGENT);
        if (old + 1u == tgt) {
          __hip_atomic_store(&bar[64], tgt, __ATOMIC_RELAXED,
                             __HIP_MEMORY_SCOPE_AGENT);
        } else {
          while (__hip_atomic_load(&bar[64], __ATOMIC_RELAXED,
                                   __HIP_MEMORY_SCOPE_AGENT) < tgt)
            __builtin_amdgcn_s_sleep(4);
        }
      }
      __syncthreads();
    }
  }
  cws[cb * HID + jglob] = creg;
}

extern "C" void kernel_launch(void* const* d_in, const int* in_sizes, int n_in,
                              void* d_out, int out_size, void* d_ws, size_t ws_size,
                              hipStream_t stream) {
  const float* x   = (const float*)d_in[0];
  const float* h0  = (const float*)d_in[1];
  const float* c0  = (const float*)d_in[2];
  const float* Wih = (const float*)d_in[3];
  const float* bih = (const float*)d_in[4];
  const float* Whh = (const float*)d_in[5];
  const float* bhh = (const float*)d_in[6];
  float* out = (float*)d_out;

  const size_t OFF_OUTPUT = 0;                  // (512,64,1024)
  const size_t OFF_HT   = 33554432;             // (2,64,1024)
  const size_t OFF_CT   = OFF_HT + 131072;      // (2,64,8,128)
  const size_t OFF_OUTS = OFF_CT + 131072;      // (2,512,64,1024)
  const size_t OFF_DFS  = OFF_OUTS + 67108864;  // (2,512,64)
  const size_t OFF_DINS = OFF_DFS + 65536;      // (2,512,64)

  uint8_t* ws = (uint8_t*)d_ws;
  size_t off = 0;
  auto alloc = [&](size_t bytes) { size_t p = off; off = (off + bytes + 255) & ~(size_t)255; return p; };
  const size_t wT_sz = (size_t)GSZ * HID * 2;
  size_t o_WihT[2], o_WhhT[2];
  o_WihT[0] = alloc(wT_sz); o_WihT[1] = alloc(wT_sz);
  o_WhhT[0] = alloc(wT_sz); o_WhhT[1] = alloc(wT_sz);
  size_t o_h0b = alloc((size_t)BATCH * HID * 2);
  size_t o_h1b = alloc((size_t)BATCH * HID * 2);
  size_t o_c   = alloc((size_t)BATCH * HID * 4);
  size_t o_bar = alloc(512);
  size_t fixed = off;
  // per-step unit: prevb (bf16) + tin (bf16, transposed)
  const size_t unit = (size_t)BATCH * HID * 2 + (size_t)BATCH * GSZ * 2 + 512;
  int TC = 256;
  while (TC > 2 && fixed + (size_t)TC * unit > ws_size) TC >>= 1;
  size_t o_prevb = alloc((size_t)TC * BATCH * HID * 2);
  size_t o_tin   = alloc((size_t)TC * BATCH * GSZ * 2);

  ushort* hb0 = (ushort*)(ws + o_h0b);
  ushort* hb1 = (ushort*)(ws + o_h1b);
  float*  cst = (float*)(ws + o_c);
  unsigned* bar = (unsigned*)(ws + o_bar);
  ushort* prevb = (ushort*)(ws + o_prevb);
  ushort* tin   = (ushort*)(ws + o_tin);

  dim3 tgrid((GSZ + 31) / 32, HID / 32);
  for (int l = 0; l < 2; ++l) {
    k_transpose_cast<<<tgrid, 256, 0, stream>>>(Wih + (size_t)l * HID * GSZ,
                                                (ushort*)(ws + o_WihT[l]), HID, GSZ);
    k_transpose_cast<<<tgrid, 256, 0, stream>>>(Whh + (size_t)l * HID * GSZ,
                                                (ushort*)(ws + o_WhhT[l]), HID, GSZ);
  }

  const int NB = (GSZ + 63) / 64;
  for (int l = 0; l < 2; ++l) {
    const float* prev = (l == 0) ? x : (out + OFF_OUTS);  // layer-0 hs in outs[0]
    const ushort* WihT = (const ushort*)(ws + o_WihT[l]);

    k_init_state<<<256, 256, 0, stream>>>(h0 + (size_t)l * BATCH * HID,
                                          c0 + (size_t)l * BATCH * HID,
                                          hb0, cst, bar, BATCH * HID);

    int barbase = 0;  // cumulative barrier rounds this layer
    for (int t0 = 0; t0 < LSEQ; t0 += TC) {
      int nsteps = (LSEQ - t0 < TC) ? (LSEQ - t0) : TC;

      int count4 = nsteps * BATCH * HID / 4;
      int cblocks = (count4 + 255) / 256; if (cblocks > 2048) cblocks = 2048;
      k_cast4<<<cblocks, 256, 0, stream>>>(
          (const float4*)(prev + (size_t)t0 * BATCH * HID), prevb, count4);

      k_gemm_t<<<dim3(NB, nsteps), 256, 0, stream>>>(prevb, WihT,
                                                     bih + (size_t)l * GSZ, tin, HID, GSZ);

      bool last = (t0 + nsteps == LSEQ);
      const ushort* WhhT_p = (const ushort*)(ws + o_WhhT[l]);
      const float* bhh_p = bhh + (size_t)l * GSZ;
      const ushort* tin_p = tin;
      ushort* h0_p = hb0;
      ushort* h1_p = hb1;
      float* c_p = cst;
      float* ohs  = out + OFF_OUTS + ((size_t)l * LSEQ + t0) * BATCH * HID;
      float* ohs2 = (l == 1) ? (out + OFF_OUTPUT + (size_t)t0 * BATCH * HID) : nullptr;
      float* dfsp  = out + OFF_DFS  + ((size_t)l * LSEQ + t0) * BATCH;
      float* dinsp = out + OFF_DINS + ((size_t)l * LSEQ + t0) * BATCH;
      float* hTp = last ? (out + OFF_HT + (size_t)l * BATCH * HID) : nullptr;
      float* cTp = last ? (out + OFF_CT + (size_t)l * BATCH * HID) : nullptr;
      int nsteps_v = nsteps;
      int barbase_v = barbase;

      void* args[] = {&WhhT_p, &bhh_p, &tin_p, &h0_p, &h1_p, &c_p, &ohs, &ohs2,
                      &dfsp, &dinsp, &hTp, &cTp, &bar, &nsteps_v, &barbase_v};
      hipLaunchCooperativeKernel((const void*)k_scan, dim3(NBLK), dim3(1024),
                                 args, 0, stream);
      barbase += nsteps - 1;

      // h parity: if nsteps is odd the final h landed in the "other" buffer;
      // swap pointers so the next chunk starts from the right one.
      if (nsteps & 1) { ushort* tmp = hb0; hb0 = hb1; hb1 = tmp; }
    }
  }
}

// Round 6
// 16357.761 us; speedup vs baseline: 4.2536x; 1.7958x over previous
//
#include <hip/hip_runtime.h>
#include <math.h>

#define LSEQ 512
#define BATCH 64
#define HID 1024
#define NCH 8
#define GSZ 4112
#define NBLK 64

typedef __bf16 bf16x8 __attribute__((ext_vector_type(8)));
typedef float f32x4 __attribute__((ext_vector_type(4)));
typedef unsigned u32x4 __attribute__((ext_vector_type(4)));

__device__ __forceinline__ ushort f2b(float f) {
  union { float f; unsigned u; } v; v.f = f;
  unsigned u = v.u;
  unsigned r = (u + 0x7FFFu + ((u >> 16) & 1u)) >> 16;  // RNE
  return (ushort)r;
}
__device__ __forceinline__ float b2f(ushort h) {
  union { unsigned u; float f; } v; v.u = (unsigned)h << 16; return v.f;
}
__device__ __forceinline__ float sigmoidf(float x) { return 1.f / (1.f + expf(-x)); }

// ---- transpose + cast: W (K x N) f32 -> WT (N x K) bf16 ----
__global__ __launch_bounds__(256) void k_transpose_cast(
    const float* __restrict__ W, ushort* __restrict__ WT, int K, int N) {
  __shared__ float tile[32][33];
  int n0 = blockIdx.x * 32, k0 = blockIdx.y * 32;
  int tx = threadIdx.x & 31, ty = threadIdx.x >> 5;
  #pragma unroll
  for (int i = ty; i < 32; i += 8) {
    int n = n0 + tx;
    tile[i][tx] = (n < N) ? W[(size_t)(k0 + i) * N + n] : 0.f;
  }
  __syncthreads();
  #pragma unroll
  for (int i = ty; i < 32; i += 8) {
    int n = n0 + i;
    if (n < N) WT[(size_t)n * K + k0 + tx] = f2b(tile[tx][i]);
  }
}

// ---- f32 -> bf16 cast (vectorized x4) ----
__global__ void k_cast4(const float4* __restrict__ in, ushort* __restrict__ out, int count4) {
  int stride = gridDim.x * blockDim.x;
  for (int i = blockIdx.x * blockDim.x + threadIdx.x; i < count4; i += stride) {
    float4 v = in[i];
    ushort4 o;
    o.x = f2b(v.x); o.y = f2b(v.y); o.z = f2b(v.z); o.w = f2b(v.w);
    *reinterpret_cast<ushort4*>(out + (size_t)i * 4) = o;
  }
}

__global__ void k_init_state(const float* __restrict__ h0l, const float* __restrict__ c0l,
                             ushort* __restrict__ hb, float* __restrict__ c,
                             unsigned* __restrict__ barmem, int count) {
  int i = blockIdx.x * blockDim.x + threadIdx.x;
  if (i < count) { hb[i] = f2b(h0l[i]); c[i] = c0l[i]; }
  if (i < NBLK * 16) barmem[i] = 0u;  // per-block flag cachelines
}

// Ct[t][col][batch] (bf16) = A[t*64+b][K](bf16) @ BT[col][K](bf16)^T + bias[col]
__global__ __launch_bounds__(256) void k_gemm_t(
    const ushort* __restrict__ A, const ushort* __restrict__ BT,
    const float* __restrict__ bias, ushort* __restrict__ Ct, int K, int N) {
  int col0 = blockIdx.x * 64;
  int t = blockIdx.y;
  int lane = threadIdx.x & 63;
  int w = threadIdx.x >> 6;
  int l15 = lane & 15;
  int koff = (lane >> 4) * 8;
  const ushort* Ap = A + (size_t)(t * 64 + w * 16 + l15) * K + koff;
  const ushort* Bp[4];
  int cols[4];
  #pragma unroll
  for (int cg = 0; cg < 4; ++cg) {
    int c_ = col0 + cg * 16 + l15;
    cols[cg] = c_;
    int cc = c_ < N ? c_ : N - 1;  // clamp reads on partial tile
    Bp[cg] = BT + (size_t)cc * K + koff;
  }
  f32x4 acc[4] = {};
  #pragma unroll 4
  for (int kk = 0; kk < K; kk += 32) {
    bf16x8 a = *reinterpret_cast<const bf16x8*>(Ap + kk);
    #pragma unroll
    for (int cg = 0; cg < 4; ++cg) {
      bf16x8 b = *reinterpret_cast<const bf16x8*>(Bp[cg] + kk);
      acc[cg] = __builtin_amdgcn_mfma_f32_16x16x32_bf16(a, b, acc[cg], 0, 0, 0);
    }
  }
  int crow = w * 16 + (lane >> 4) * 4;  // batch row base
  #pragma unroll
  for (int cg = 0; cg < 4; ++cg) {
    int c_ = cols[cg];
    if (c_ >= N) continue;
    float bv = bias[c_];
    ushort4 o;
    o.x = f2b(acc[cg][0] + bv); o.y = f2b(acc[cg][1] + bv);
    o.z = f2b(acc[cg][2] + bv); o.w = f2b(acc[cg][3] + bv);
    *reinterpret_cast<ushort4*>(&Ct[((size_t)t * GSZ + c_) * 64 + crow]) = o;
  }
}

// ---- persistent scan: 64 blocks x 1024 threads (16 waves) ----
// GEMM phase: 5 waves, wave g owns ONE 16-col tile (g=0: softmax cols,
// g=1..4: out/cell/in/fg for the block's 16 hidden units) and iterates all
// 4 batch tiles, reusing each B-frag from registers (min L1 traffic).
// Barrier: per-block flag cachelines (stores) + 64-lane gather poll. No
// atomics, no L2 flush. out stores deferred past the barrier.
__global__ __launch_bounds__(1024, 4) void k_scan(
    const ushort* __restrict__ WhhT,  // [GSZ][HID] bf16
    const float* __restrict__ bhh,
    const ushort* __restrict__ tin,   // [nsteps][GSZ][64] bf16
    ushort* __restrict__ hbuf0, ushort* __restrict__ hbuf1,  // [64][1024] bf16
    float* __restrict__ cws,          // [64][1024] f32
    float* __restrict__ out_hs, float* __restrict__ out_hs2,
    float* __restrict__ dfs, float* __restrict__ dins,
    float* __restrict__ hT, float* __restrict__ cT,
    unsigned* __restrict__ barmem, int nsteps, int barbase) {
  __shared__ unsigned hlds[32768];            // 128 KB: h staged, XOR-swizzled
  __shared__ __align__(16) float gbuf[80][68];  // [col][batch]

  const int tid = threadIdx.x;
  const int blk = blockIdx.x;
  const int j0 = blk * 16;
  const int lane = tid & 63;
  const int w = tid >> 6;       // wave 0..15
  const int l15 = lane & 15;
  const int koff = (lane >> 4) * 8;

  // GEMM-wave constants (w < 5)
  const int gcol = (w == 0) ? l15 : (16 + (w - 1) * 1024 + j0 + l15);
  const ushort* bp = WhhT + (size_t)gcol * HID + koff;
  const float bv = bhh[gcol];
  const int grow = (w == 0) ? l15 : (16 + (w - 1) * 16 + l15);
  const int cr = (lane >> 4) << 2;  // batch sub-row within 16-row tile
  const unsigned ab = (unsigned)l15 * 2048u + (unsigned)koff * 2u;
  const unsigned swz = (unsigned)(l15 & 7) << 4;

  // cell mapping: thread -> (batch cb, local hidden jl)
  const int cb = tid >> 4;
  const int jl = tid & 15;
  const int jglob = j0 + jl;
  const int r = jglob >> 7;
  float creg = cws[cb * HID + jglob];

  float def_hy = 0.f, def_df = 0.f, def_di = 0.f;
  size_t def_oidx = 0;

  for (int tt = 0; tt < nsteps; ++tt) {
    // ---- (A) deferred output stores from step tt-1 (off critical path) ----
    if (tt > 0) {
      out_hs[def_oidx] = def_hy;
      if (out_hs2) out_hs2[def_oidx] = def_hy;
      if (blk == 0 && jl == 0) {
        dfs[(tt - 1) * BATCH + cb] = def_df;
        dins[(tt - 1) * BATCH + cb] = def_di;
      }
    }

    // ---- (B/C) stage h (coherent LLC read) -> LDS, swizzled ----
    const u32x4* hs = (const u32x4*)((tt & 1) ? hbuf1 : hbuf0);
    u32x4 v0, v1, v2, v3, v4, v5, v6, v7;
#define CLOAD(dst, I) asm volatile("global_load_dwordx4 %0, %1, off sc0 sc1" \
      : "=v"(dst) : "v"(hs + tid + (I)*1024) : "memory")
    CLOAD(v0, 0); CLOAD(v1, 1); CLOAD(v2, 2); CLOAD(v3, 3);
    CLOAD(v4, 4); CLOAD(v5, 5); CLOAD(v6, 6); CLOAD(v7, 7);
#undef CLOAD
    asm volatile("s_waitcnt vmcnt(0)" ::: "memory");
    __builtin_amdgcn_sched_barrier(0);
#define WST(v, I) { unsigned byte_ = (unsigned)(tid + (I)*1024) * 16u; \
    unsigned row_ = byte_ >> 11; \
    *(u32x4*)((char*)hlds + (byte_ ^ ((row_ & 7u) << 4))) = v; }
    WST(v0, 0); WST(v1, 1); WST(v2, 2); WST(v3, 3);
    WST(v4, 4); WST(v5, 5); WST(v6, 6); WST(v7, 7);
#undef WST
    __syncthreads();

    // ---- (D) GEMM: 5 waves, one col-tile each, 4 batch tiles ----
    if (w < 5) {
      const ushort* tp = tin + ((size_t)tt * GSZ + gcol) * 64 + cr;
      ushort4 tv0 = *(const ushort4*)(tp);
      ushort4 tv1 = *(const ushort4*)(tp + 16);
      ushort4 tv2 = *(const ushort4*)(tp + 32);
      ushort4 tv3 = *(const ushort4*)(tp + 48);
      f32x4 a0 = {}, a1 = {}, a2 = {}, a3 = {};
      #pragma unroll 4
      for (int kb = 0; kb < 32; ++kb) {
        bf16x8 b = *(const bf16x8*)(bp + kb * 32);
        unsigned o = ab + (unsigned)kb * 64u;
        bf16x8 x0 = *(const bf16x8*)((const char*)hlds + ((o)           ^ swz));
        bf16x8 x1 = *(const bf16x8*)((const char*)hlds + ((o + 32768u)  ^ swz));
        bf16x8 x2 = *(const bf16x8*)((const char*)hlds + ((o + 65536u)  ^ swz));
        bf16x8 x3 = *(const bf16x8*)((const char*)hlds + ((o + 98304u)  ^ swz));
        a0 = __builtin_amdgcn_mfma_f32_16x16x32_bf16(x0, b, a0, 0, 0, 0);
        a1 = __builtin_amdgcn_mfma_f32_16x16x32_bf16(x1, b, a1, 0, 0, 0);
        a2 = __builtin_amdgcn_mfma_f32_16x16x32_bf16(x2, b, a2, 0, 0, 0);
        a3 = __builtin_amdgcn_mfma_f32_16x16x32_bf16(x3, b, a3, 0, 0, 0);
      }
      f32x4 g;
      g[0] = a0[0] + bv + b2f(tv0.x); g[1] = a0[1] + bv + b2f(tv0.y);
      g[2] = a0[2] + bv + b2f(tv0.z); g[3] = a0[3] + bv + b2f(tv0.w);
      *(f32x4*)(&gbuf[grow][cr]) = g;
      g[0] = a1[0] + bv + b2f(tv1.x); g[1] = a1[1] + bv + b2f(tv1.y);
      g[2] = a1[2] + bv + b2f(tv1.z); g[3] = a1[3] + bv + b2f(tv1.w);
      *(f32x4*)(&gbuf[grow][16 + cr]) = g;
      g[0] = a2[0] + bv + b2f(tv2.x); g[1] = a2[1] + bv + b2f(tv2.y);
      g[2] = a2[2] + bv + b2f(tv2.z); g[3] = a2[3] + bv + b2f(tv2.w);
      *(f32x4*)(&gbuf[grow][32 + cr]) = g;
      g[0] = a3[0] + bv + b2f(tv3.x); g[1] = a3[1] + bv + b2f(tv3.y);
      g[2] = a3[2] + bv + b2f(tv3.z); g[3] = a3[3] + bv + b2f(tv3.w);
      *(f32x4*)(&gbuf[grow][48 + cr]) = g;
    }
    __syncthreads();

    // ---- (E) fused cell update (all 1024 threads) ----
    float sm0[NCH], sm1[NCH];
    float m1 = -1e30f, m2 = -1e30f;
    #pragma unroll
    for (int i = 0; i < NCH; ++i) {
      sm0[i] = gbuf[i][cb];
      sm1[i] = gbuf[NCH + i][cb];
      m1 = fmaxf(m1, sm0[i]);
      m2 = fmaxf(m2, sm1[i]);
    }
    float s1 = 0.f, s2 = 0.f;
    #pragma unroll
    for (int i = 0; i < NCH; ++i) {
      sm0[i] = expf(sm0[i] - m1); s1 += sm0[i];
      sm1[i] = expf(sm1[i] - m2); s2 += sm1[i];
    }
    float r1 = 1.f / s1, r2 = 1.f / s2;
    float cum1 = 0.f, cum2 = 0.f, sumin = 0.f, sumfg = 0.f;
    float cing[NCH], cfg[NCH];
    #pragma unroll
    for (int i = 0; i < NCH; ++i) {
      cum1 += sm0[i] * r1; cing[i] = 1.f - cum1; sumin += cing[i];
      cum2 += sm1[i] * r2; cfg[i] = cum2; sumfg += cfg[i];
    }
    float go = gbuf[16 + jl][cb];
    float gc = gbuf[32 + jl][cb];
    float gi = gbuf[48 + jl][cb];
    float gf = gbuf[64 + jl][cb];
    float ov = cfg[r] * cing[r];
    float f_ = sigmoidf(gf) * ov + (cfg[r] - ov);
    float i_ = sigmoidf(gi) * ov + (cing[r] - ov);
    float cy = f_ * creg + i_ * tanhf(gc);
    float hy = sigmoidf(go) * tanhf(cy);
    creg = cy;

    // ---- (F) h store: write-through to LLC, packed bf16 pairs ----
    ushort hv = f2b(hy);
    unsigned other = (unsigned)__shfl_xor((int)(unsigned)hv, 1, 64);
    ushort* hw = ((tt & 1) ? hbuf0 : hbuf1) + cb * HID + j0 + jl;
    if ((jl & 1) == 0) {
      unsigned pk = (unsigned)hv | (other << 16);
      asm volatile("global_store_dword %0, %1, off sc0 sc1" :: "v"(hw), "v"(pk) : "memory");
    }
    if (hT && tt == nsteps - 1) {
      hT[cb * HID + jglob] = hy;
      cT[cb * HID + jglob] = cy;
    }

    // ---- (G) defer output stores to next iteration ----
    def_hy = hy;
    def_oidx = ((size_t)tt * BATCH + cb) * HID + jglob;
    def_df = 1.f - sumfg * 0.125f;
    def_di = sumin * 0.125f;

    // ---- (H) flag barrier: own-line store + 64-lane gather poll ----
    if (tt < nsteps - 1) {
      asm volatile("s_waitcnt vmcnt(0)" ::: "memory");  // h store at LLC
      __syncthreads();
      if (w == 0) {
        unsigned tgt = (unsigned)(barbase + tt + 1);
        if (lane == 0) {
          unsigned* fp = barmem + (unsigned)blk * 16u;
          asm volatile("global_store_dword %0, %1, off sc0 sc1"
                       :: "v"(fp), "v"(tgt) : "memory");
        }
        const unsigned* mp = barmem + (unsigned)lane * 16u;
        while (true) {
          unsigned f;
          asm volatile("global_load_dword %0, %1, off sc0 sc1"
                       : "=v"(f) : "v"(mp) : "memory");
          asm volatile("s_waitcnt vmcnt(0)" ::: "memory");
          if (__all((int)(f >= tgt))) break;
        }
      }
      __syncthreads();
    }
  }
  // flush deferred stores of the last step
  out_hs[def_oidx] = def_hy;
  if (out_hs2) out_hs2[def_oidx] = def_hy;
  if (blk == 0 && jl == 0) {
    dfs[(nsteps - 1) * BATCH + cb] = def_df;
    dins[(nsteps - 1) * BATCH + cb] = def_di;
  }
  cws[cb * HID + jglob] = creg;
}

extern "C" void kernel_launch(void* const* d_in, const int* in_sizes, int n_in,
                              void* d_out, int out_size, void* d_ws, size_t ws_size,
                              hipStream_t stream) {
  const float* x   = (const float*)d_in[0];
  const float* h0  = (const float*)d_in[1];
  const float* c0  = (const float*)d_in[2];
  const float* Wih = (const float*)d_in[3];
  const float* bih = (const float*)d_in[4];
  const float* Whh = (const float*)d_in[5];
  const float* bhh = (const float*)d_in[6];
  float* out = (float*)d_out;

  const size_t OFF_OUTPUT = 0;                  // (512,64,1024)
  const size_t OFF_HT   = 33554432;             // (2,64,1024)
  const size_t OFF_CT   = OFF_HT + 131072;      // (2,64,8,128)
  const size_t OFF_OUTS = OFF_CT + 131072;      // (2,512,64,1024)
  const size_t OFF_DFS  = OFF_OUTS + 67108864;  // (2,512,64)
  const size_t OFF_DINS = OFF_DFS + 65536;      // (2,512,64)

  uint8_t* ws = (uint8_t*)d_ws;
  size_t off = 0;
  auto alloc = [&](size_t bytes) { size_t p = off; off = (off + bytes + 255) & ~(size_t)255; return p; };
  const size_t wT_sz = (size_t)GSZ * HID * 2;
  size_t o_WihT[2], o_WhhT[2];
  o_WihT[0] = alloc(wT_sz); o_WihT[1] = alloc(wT_sz);
  o_WhhT[0] = alloc(wT_sz); o_WhhT[1] = alloc(wT_sz);
  size_t o_h0b = alloc((size_t)BATCH * HID * 2);
  size_t o_h1b = alloc((size_t)BATCH * HID * 2);
  size_t o_c   = alloc((size_t)BATCH * HID * 4);
  size_t o_bar = alloc(4096);
  size_t fixed = off;
  const size_t unit = (size_t)BATCH * HID * 2 + (size_t)BATCH * GSZ * 2 + 512;
  int TC = 256;
  while (TC > 2 && fixed + (size_t)TC * unit > ws_size) TC >>= 1;
  size_t o_prevb = alloc((size_t)TC * BATCH * HID * 2);
  size_t o_tin   = alloc((size_t)TC * BATCH * GSZ * 2);

  ushort* hb0 = (ushort*)(ws + o_h0b);
  ushort* hb1 = (ushort*)(ws + o_h1b);
  float*  cst = (float*)(ws + o_c);
  unsigned* barmem = (unsigned*)(ws + o_bar);
  ushort* prevb = (ushort*)(ws + o_prevb);
  ushort* tin   = (ushort*)(ws + o_tin);

  dim3 tgrid((GSZ + 31) / 32, HID / 32);
  for (int l = 0; l < 2; ++l) {
    k_transpose_cast<<<tgrid, 256, 0, stream>>>(Wih + (size_t)l * HID * GSZ,
                                                (ushort*)(ws + o_WihT[l]), HID, GSZ);
    k_transpose_cast<<<tgrid, 256, 0, stream>>>(Whh + (size_t)l * HID * GSZ,
                                                (ushort*)(ws + o_WhhT[l]), HID, GSZ);
  }

  const int NB = (GSZ + 63) / 64;
  for (int l = 0; l < 2; ++l) {
    const float* prev = (l == 0) ? x : (out + OFF_OUTS);  // layer-0 hs in outs[0]
    const ushort* WihT = (const ushort*)(ws + o_WihT[l]);

    k_init_state<<<256, 256, 0, stream>>>(h0 + (size_t)l * BATCH * HID,
                                          c0 + (size_t)l * BATCH * HID,
                                          hb0, cst, barmem, BATCH * HID);

    int barbase = 0;  // cumulative barrier rounds this layer
    for (int t0 = 0; t0 < LSEQ; t0 += TC) {
      int nsteps = (LSEQ - t0 < TC) ? (LSEQ - t0) : TC;

      int count4 = nsteps * BATCH * HID / 4;
      int cblocks = (count4 + 255) / 256; if (cblocks > 2048) cblocks = 2048;
      k_cast4<<<cblocks, 256, 0, stream>>>(
          (const float4*)(prev + (size_t)t0 * BATCH * HID), prevb, count4);

      k_gemm_t<<<dim3(NB, nsteps), 256, 0, stream>>>(prevb, WihT,
                                                     bih + (size_t)l * GSZ, tin, HID, GSZ);

      bool last = (t0 + nsteps == LSEQ);
      const ushort* WhhT_p = (const ushort*)(ws + o_WhhT[l]);
      const float* bhh_p = bhh + (size_t)l * GSZ;
      const ushort* tin_p = tin;
      ushort* h0_p = hb0;
      ushort* h1_p = hb1;
      float* c_p = cst;
      float* ohs  = out + OFF_OUTS + ((size_t)l * LSEQ + t0) * BATCH * HID;
      float* ohs2 = (l == 1) ? (out + OFF_OUTPUT + (size_t)t0 * BATCH * HID) : nullptr;
      float* dfsp  = out + OFF_DFS  + ((size_t)l * LSEQ + t0) * BATCH;
      float* dinsp = out + OFF_DINS + ((size_t)l * LSEQ + t0) * BATCH;
      float* hTp = last ? (out + OFF_HT + (size_t)l * BATCH * HID) : nullptr;
      float* cTp = last ? (out + OFF_CT + (size_t)l * BATCH * HID) : nullptr;
      int nsteps_v = nsteps;
      int barbase_v = barbase;

      void* args[] = {&WhhT_p, &bhh_p, &tin_p, &h0_p, &h1_p, &c_p, &ohs, &ohs2,
                      &dfsp, &dinsp, &hTp, &cTp, &barmem, &nsteps_v, &barbase_v};
      hipLaunchCooperativeKernel((const void*)k_scan, dim3(NBLK), dim3(1024),
                                 args, 0, stream);
      barbase += nsteps - 1;

      // h parity: if nsteps is odd the final h landed in the "other" buffer
      if (nsteps & 1) { ushort* tmp = hb0; hb0 = hb1; hb1 = tmp; }
    }
  }
}

// Round 7
// 16273.120 us; speedup vs baseline: 4.2757x; 1.0052x over previous
//
#include <hip/hip_runtime.h>
#include <math.h>

#define LSEQ 512
#define BATCH 64
#define HID 1024
#define NCH 8
#define GSZ 4112
#define NBLK 64

typedef __bf16 bf16x8 __attribute__((ext_vector_type(8)));
typedef float f32x4 __attribute__((ext_vector_type(4)));
typedef unsigned u32x4 __attribute__((ext_vector_type(4)));

__device__ __forceinline__ ushort f2b(float f) {
  union { float f; unsigned u; } v; v.f = f;
  unsigned u = v.u;
  unsigned r = (u + 0x7FFFu + ((u >> 16) & 1u)) >> 16;  // RNE
  return (ushort)r;
}
__device__ __forceinline__ float b2f(ushort h) {
  union { unsigned u; float f; } v; v.u = (unsigned)h << 16; return v.f;
}
__device__ __forceinline__ float sigmoidf(float x) { return 1.f / (1.f + expf(-x)); }

// ---- transpose + cast: W (K x N) f32 -> WT (N x K) bf16 ----
__global__ __launch_bounds__(256) void k_transpose_cast(
    const float* __restrict__ W, ushort* __restrict__ WT, int K, int N) {
  __shared__ float tile[32][33];
  int n0 = blockIdx.x * 32, k0 = blockIdx.y * 32;
  int tx = threadIdx.x & 31, ty = threadIdx.x >> 5;
  #pragma unroll
  for (int i = ty; i < 32; i += 8) {
    int n = n0 + tx;
    tile[i][tx] = (n < N) ? W[(size_t)(k0 + i) * N + n] : 0.f;
  }
  __syncthreads();
  #pragma unroll
  for (int i = ty; i < 32; i += 8) {
    int n = n0 + i;
    if (n < N) WT[(size_t)n * K + k0 + tx] = f2b(tile[tx][i]);
  }
}

// ---- f32 -> bf16 cast (vectorized x4) ----
__global__ void k_cast4(const float4* __restrict__ in, ushort* __restrict__ out, int count4) {
  int stride = gridDim.x * blockDim.x;
  for (int i = blockIdx.x * blockDim.x + threadIdx.x; i < count4; i += stride) {
    float4 v = in[i];
    ushort4 o;
    o.x = f2b(v.x); o.y = f2b(v.y); o.z = f2b(v.z); o.w = f2b(v.w);
    *reinterpret_cast<ushort4*>(out + (size_t)i * 4) = o;
  }
}

__global__ void k_init_state(const float* __restrict__ h0l, const float* __restrict__ c0l,
                             ushort* __restrict__ hb, float* __restrict__ c,
                             unsigned* __restrict__ barmem, int count) {
  int i = blockIdx.x * blockDim.x + threadIdx.x;
  if (i < count) { hb[i] = f2b(h0l[i]); c[i] = c0l[i]; }
  if (i < NBLK * 16) barmem[i] = 0u;  // per-block flag cachelines
}

// Ct[t][col][batch] (bf16) = A[t*64+b][K](bf16) @ BT[col][K](bf16)^T + bias[col]
__global__ __launch_bounds__(256) void k_gemm_t(
    const ushort* __restrict__ A, const ushort* __restrict__ BT,
    const float* __restrict__ bias, ushort* __restrict__ Ct, int K, int N) {
  int col0 = blockIdx.x * 64;
  int t = blockIdx.y;
  int lane = threadIdx.x & 63;
  int w = threadIdx.x >> 6;
  int l15 = lane & 15;
  int koff = (lane >> 4) * 8;
  const ushort* Ap = A + (size_t)(t * 64 + w * 16 + l15) * K + koff;
  const ushort* Bp[4];
  int cols[4];
  #pragma unroll
  for (int cg = 0; cg < 4; ++cg) {
    int c_ = col0 + cg * 16 + l15;
    cols[cg] = c_;
    int cc = c_ < N ? c_ : N - 1;  // clamp reads on partial tile
    Bp[cg] = BT + (size_t)cc * K + koff;
  }
  f32x4 acc[4] = {};
  #pragma unroll 4
  for (int kk = 0; kk < K; kk += 32) {
    bf16x8 a = *reinterpret_cast<const bf16x8*>(Ap + kk);
    #pragma unroll
    for (int cg = 0; cg < 4; ++cg) {
      bf16x8 b = *reinterpret_cast<const bf16x8*>(Bp[cg] + kk);
      acc[cg] = __builtin_amdgcn_mfma_f32_16x16x32_bf16(a, b, acc[cg], 0, 0, 0);
    }
  }
  int crow = w * 16 + (lane >> 4) * 4;  // batch row base
  #pragma unroll
  for (int cg = 0; cg < 4; ++cg) {
    int c_ = cols[cg];
    if (c_ >= N) continue;
    float bv = bias[c_];
    ushort4 o;
    o.x = f2b(acc[cg][0] + bv); o.y = f2b(acc[cg][1] + bv);
    o.z = f2b(acc[cg][2] + bv); o.w = f2b(acc[cg][3] + bv);
    *reinterpret_cast<ushort4*>(&Ct[((size_t)t * GSZ + c_) * 64 + crow]) = o;
  }
}

// ---- persistent scan: 64 blocks x 1024 threads (16 waves) ----
// GEMM phase: 5 waves, wave g owns ONE 16-col tile (g=0: softmax cols,
// g=1..4: out/cell/in/fg for the block's 16 hidden units) and iterates all
// 4 batch tiles, reusing each B-frag from registers (min L1 traffic).
// Barrier: per-block flag cachelines (stores) + 64-lane gather poll. No
// atomics, no L2 flush. out stores deferred past the barrier.
__global__ __launch_bounds__(1024, 4) void k_scan(
    const ushort* __restrict__ WhhT,  // [GSZ][HID] bf16
    const float* __restrict__ bhh,
    const ushort* __restrict__ tin,   // [nsteps][GSZ][64] bf16
    ushort* __restrict__ hbuf0, ushort* __restrict__ hbuf1,  // [64][1024] bf16
    float* __restrict__ cws,          // [64][1024] f32
    float* __restrict__ out_hs, float* __restrict__ out_hs2,
    float* __restrict__ dfs, float* __restrict__ dins,
    float* __restrict__ hT, float* __restrict__ cT,
    unsigned* __restrict__ barmem, int nsteps, int barbase) {
  __shared__ unsigned hlds[32768];            // 128 KB: h staged, XOR-swizzled
  __shared__ __align__(16) float gbuf[80][68];  // [col][batch]

  const int tid = threadIdx.x;
  const int blk = blockIdx.x;
  const int j0 = blk * 16;
  const int lane = tid & 63;
  const int w = tid >> 6;       // wave 0..15
  const int l15 = lane & 15;
  const int koff = (lane >> 4) * 8;

  // GEMM-wave constants (w < 5)
  const int gcol = (w == 0) ? l15 : (16 + (w - 1) * 1024 + j0 + l15);
  const ushort* bp = WhhT + (size_t)gcol * HID + koff;
  const float bv = bhh[gcol];
  const int grow = (w == 0) ? l15 : (16 + (w - 1) * 16 + l15);
  const int cr = (lane >> 4) << 2;  // batch sub-row within 16-row tile
  const unsigned ab = (unsigned)l15 * 2048u + (unsigned)koff * 2u;
  const unsigned swz = (unsigned)(l15 & 7) << 4;

  // cell mapping: thread -> (batch cb, local hidden jl)
  const int cb = tid >> 4;
  const int jl = tid & 15;
  const int jglob = j0 + jl;
  const int r = jglob >> 7;
  float creg = cws[cb * HID + jglob];

  float def_hy = 0.f, def_df = 0.f, def_di = 0.f;
  size_t def_oidx = 0;

  for (int tt = 0; tt < nsteps; ++tt) {
    // ---- (A) deferred output stores from step tt-1 (off critical path) ----
    if (tt > 0) {
      out_hs[def_oidx] = def_hy;
      if (out_hs2) out_hs2[def_oidx] = def_hy;
      if (blk == 0 && jl == 0) {
        dfs[(tt - 1) * BATCH + cb] = def_df;
        dins[(tt - 1) * BATCH + cb] = def_di;
      }
    }

    // ---- (B/C) stage h (coherent LLC read) -> LDS, swizzled ----
    const u32x4* hs = (const u32x4*)((tt & 1) ? hbuf1 : hbuf0);
    u32x4 v0, v1, v2, v3, v4, v5, v6, v7;
#define CLOAD(dst, I) asm volatile("global_load_dwordx4 %0, %1, off sc0 sc1" \
      : "=v"(dst) : "v"(hs + tid + (I)*1024) : "memory")
    CLOAD(v0, 0); CLOAD(v1, 1); CLOAD(v2, 2); CLOAD(v3, 3);
    CLOAD(v4, 4); CLOAD(v5, 5); CLOAD(v6, 6); CLOAD(v7, 7);
#undef CLOAD
    asm volatile("s_waitcnt vmcnt(0)" ::: "memory");
    __builtin_amdgcn_sched_barrier(0);
#define WST(v, I) { unsigned byte_ = (unsigned)(tid + (I)*1024) * 16u; \
    unsigned row_ = byte_ >> 11; \
    *(u32x4*)((char*)hlds + (byte_ ^ ((row_ & 7u) << 4))) = v; }
    WST(v0, 0); WST(v1, 1); WST(v2, 2); WST(v3, 3);
    WST(v4, 4); WST(v5, 5); WST(v6, 6); WST(v7, 7);
#undef WST
    __syncthreads();

    // ---- (D) GEMM: 5 waves, one col-tile each, 4 batch tiles ----
    if (w < 5) {
      const ushort* tp = tin + ((size_t)tt * GSZ + gcol) * 64 + cr;
      ushort4 tv0 = *(const ushort4*)(tp);
      ushort4 tv1 = *(const ushort4*)(tp + 16);
      ushort4 tv2 = *(const ushort4*)(tp + 32);
      ushort4 tv3 = *(const ushort4*)(tp + 48);
      f32x4 a0 = {}, a1 = {}, a2 = {}, a3 = {};
      #pragma unroll 4
      for (int kb = 0; kb < 32; ++kb) {
        bf16x8 b = *(const bf16x8*)(bp + kb * 32);
        unsigned o = ab + (unsigned)kb * 64u;
        bf16x8 x0 = *(const bf16x8*)((const char*)hlds + ((o)           ^ swz));
        bf16x8 x1 = *(const bf16x8*)((const char*)hlds + ((o + 32768u)  ^ swz));
        bf16x8 x2 = *(const bf16x8*)((const char*)hlds + ((o + 65536u)  ^ swz));
        bf16x8 x3 = *(const bf16x8*)((const char*)hlds + ((o + 98304u)  ^ swz));
        a0 = __builtin_amdgcn_mfma_f32_16x16x32_bf16(x0, b, a0, 0, 0, 0);
        a1 = __builtin_amdgcn_mfma_f32_16x16x32_bf16(x1, b, a1, 0, 0, 0);
        a2 = __builtin_amdgcn_mfma_f32_16x16x32_bf16(x2, b, a2, 0, 0, 0);
        a3 = __builtin_amdgcn_mfma_f32_16x16x32_bf16(x3, b, a3, 0, 0, 0);
      }
      f32x4 g;
      g[0] = a0[0] + bv + b2f(tv0.x); g[1] = a0[1] + bv + b2f(tv0.y);
      g[2] = a0[2] + bv + b2f(tv0.z); g[3] = a0[3] + bv + b2f(tv0.w);
      *(f32x4*)(&gbuf[grow][cr]) = g;
      g[0] = a1[0] + bv + b2f(tv1.x); g[1] = a1[1] + bv + b2f(tv1.y);
      g[2] = a1[2] + bv + b2f(tv1.z); g[3] = a1[3] + bv + b2f(tv1.w);
      *(f32x4*)(&gbuf[grow][16 + cr]) = g;
      g[0] = a2[0] + bv + b2f(tv2.x); g[1] = a2[1] + bv + b2f(tv2.y);
      g[2] = a2[2] + bv + b2f(tv2.z); g[3] = a2[3] + bv + b2f(tv2.w);
      *(f32x4*)(&gbuf[grow][32 + cr]) = g;
      g[0] = a3[0] + bv + b2f(tv3.x); g[1] = a3[1] + bv + b2f(tv3.y);
      g[2] = a3[2] + bv + b2f(tv3.z); g[3] = a3[3] + bv + b2f(tv3.w);
      *(f32x4*)(&gbuf[grow][48 + cr]) = g;
    }
    __syncthreads();

    // ---- (E) fused cell update (all 1024 threads) ----
    float sm0[NCH], sm1[NCH];
    float m1 = -1e30f, m2 = -1e30f;
    #pragma unroll
    for (int i = 0; i < NCH; ++i) {
      sm0[i] = gbuf[i][cb];
      sm1[i] = gbuf[NCH + i][cb];
      m1 = fmaxf(m1, sm0[i]);
      m2 = fmaxf(m2, sm1[i]);
    }
    float s1 = 0.f, s2 = 0.f;
    #pragma unroll
    for (int i = 0; i < NCH; ++i) {
      sm0[i] = expf(sm0[i] - m1); s1 += sm0[i];
      sm1[i] = expf(sm1[i] - m2); s2 += sm1[i];
    }
    float r1 = 1.f / s1, r2 = 1.f / s2;
    float cum1 = 0.f, cum2 = 0.f, sumin = 0.f, sumfg = 0.f;
    float cing[NCH], cfg[NCH];
    #pragma unroll
    for (int i = 0; i < NCH; ++i) {
      cum1 += sm0[i] * r1; cing[i] = 1.f - cum1; sumin += cing[i];
      cum2 += sm1[i] * r2; cfg[i] = cum2; sumfg += cfg[i];
    }
    float go = gbuf[16 + jl][cb];
    float gc = gbuf[32 + jl][cb];
    float gi = gbuf[48 + jl][cb];
    float gf = gbuf[64 + jl][cb];
    float ov = cfg[r] * cing[r];
    float f_ = sigmoidf(gf) * ov + (cfg[r] - ov);
    float i_ = sigmoidf(gi) * ov + (cing[r] - ov);
    float cy = f_ * creg + i_ * tanhf(gc);
    float hy = sigmoidf(go) * tanhf(cy);
    creg = cy;

    // ---- (F) h store: write-through to LLC, packed bf16 pairs ----
    ushort hv = f2b(hy);
    unsigned other = (unsigned)__shfl_xor((int)(unsigned)hv, 1, 64);
    ushort* hw = ((tt & 1) ? hbuf0 : hbuf1) + cb * HID + j0 + jl;
    if ((jl & 1) == 0) {
      unsigned pk = (unsigned)hv | (other << 16);
      asm volatile("global_store_dword %0, %1, off sc0 sc1" :: "v"(hw), "v"(pk) : "memory");
    }
    if (hT && tt == nsteps - 1) {
      hT[cb * HID + jglob] = hy;
      cT[cb * HID + jglob] = cy;
    }

    // ---- (G) defer output stores to next iteration ----
    def_hy = hy;
    def_oidx = ((size_t)tt * BATCH + cb) * HID + jglob;
    def_df = 1.f - sumfg * 0.125f;
    def_di = sumin * 0.125f;

    // ---- (H) flag barrier: own-line store + 64-lane gather poll ----
    if (tt < nsteps - 1) {
      asm volatile("s_waitcnt vmcnt(0)" ::: "memory");  // h store at LLC
      __syncthreads();
      if (w == 0) {
        unsigned tgt = (unsigned)(barbase + tt + 1);
        if (lane == 0) {
          unsigned* fp = barmem + (unsigned)blk * 16u;
          asm volatile("global_store_dword %0, %1, off sc0 sc1"
                       :: "v"(fp), "v"(tgt) : "memory");
        }
        const unsigned* mp = barmem + (unsigned)lane * 16u;
        while (true) {
          unsigned f;
          asm volatile("global_load_dword %0, %1, off sc0 sc1"
                       : "=v"(f) : "v"(mp) : "memory");
          asm volatile("s_waitcnt vmcnt(0)" ::: "memory");
          if (__all((int)(f >= tgt))) break;
        }
      }
      __syncthreads();
    }
  }
  // flush deferred stores of the last step
  out_hs[def_oidx] = def_hy;
  if (out_hs2) out_hs2[def_oidx] = def_hy;
  if (blk == 0 && jl == 0) {
    dfs[(nsteps - 1) * BATCH + cb] = def_df;
    dins[(nsteps - 1) * BATCH + cb] = def_di;
  }
  cws[cb * HID + jglob] = creg;
}

extern "C" void kernel_launch(void* const* d_in, const int* in_sizes, int n_in,
                              void* d_out, int out_size, void* d_ws, size_t ws_size,
                              hipStream_t stream) {
  const float* x   = (const float*)d_in[0];
  const float* h0  = (const float*)d_in[1];
  const float* c0  = (const float*)d_in[2];
  const float* Wih = (const float*)d_in[3];
  const float* bih = (const float*)d_in[4];
  const float* Whh = (const float*)d_in[5];
  const float* bhh = (const float*)d_in[6];
  float* out = (float*)d_out;

  const size_t OFF_OUTPUT = 0;                  // (512,64,1024)
  const size_t OFF_HT   = 33554432;             // (2,64,1024)
  const size_t OFF_CT   = OFF_HT + 131072;      // (2,64,8,128)
  const size_t OFF_OUTS = OFF_CT + 131072;      // (2,512,64,1024)
  const size_t OFF_DFS  = OFF_OUTS + 67108864;  // (2,512,64)
  const size_t OFF_DINS = OFF_DFS + 65536;      // (2,512,64)

  uint8_t* ws = (uint8_t*)d_ws;
  size_t off = 0;
  auto alloc = [&](size_t bytes) { size_t p = off; off = (off + bytes + 255) & ~(size_t)255; return p; };
  const size_t wT_sz = (size_t)GSZ * HID * 2;
  size_t o_WihT[2], o_WhhT[2];
  o_WihT[0] = alloc(wT_sz); o_WihT[1] = alloc(wT_sz);
  o_WhhT[0] = alloc(wT_sz); o_WhhT[1] = alloc(wT_sz);
  size_t o_h0b = alloc((size_t)BATCH * HID * 2);
  size_t o_h1b = alloc((size_t)BATCH * HID * 2);
  size_t o_c   = alloc((size_t)BATCH * HID * 4);
  size_t o_bar = alloc(4096);
  size_t fixed = off;
  const size_t unit = (size_t)BATCH * HID * 2 + (size_t)BATCH * GSZ * 2 + 512;
  int TC = 256;
  while (TC > 2 && fixed + (size_t)TC * unit > ws_size) TC >>= 1;
  size_t o_prevb = alloc((size_t)TC * BATCH * HID * 2);
  size_t o_tin   = alloc((size_t)TC * BATCH * GSZ * 2);

  ushort* hb0 = (ushort*)(ws + o_h0b);
  ushort* hb1 = (ushort*)(ws + o_h1b);
  float*  cst = (float*)(ws + o_c);
  unsigned* barmem = (unsigned*)(ws + o_bar);
  ushort* prevb = (ushort*)(ws + o_prevb);
  ushort* tin   = (ushort*)(ws + o_tin);

  dim3 tgrid((GSZ + 31) / 32, HID / 32);
  for (int l = 0; l < 2; ++l) {
    k_transpose_cast<<<tgrid, 256, 0, stream>>>(Wih + (size_t)l * HID * GSZ,
                                                (ushort*)(ws + o_WihT[l]), HID, GSZ);
    k_transpose_cast<<<tgrid, 256, 0, stream>>>(Whh + (size_t)l * HID * GSZ,
                                                (ushort*)(ws + o_WhhT[l]), HID, GSZ);
  }

  const int NB = (GSZ + 63) / 64;
  for (int l = 0; l < 2; ++l) {
    const float* prev = (l == 0) ? x : (out + OFF_OUTS);  // layer-0 hs in outs[0]
    const ushort* WihT = (const ushort*)(ws + o_WihT[l]);

    k_init_state<<<256, 256, 0, stream>>>(h0 + (size_t)l * BATCH * HID,
                                          c0 + (size_t)l * BATCH * HID,
                                          hb0, cst, barmem, BATCH * HID);

    int barbase = 0;  // cumulative barrier rounds this layer
    for (int t0 = 0; t0 < LSEQ; t0 += TC) {
      int nsteps = (LSEQ - t0 < TC) ? (LSEQ - t0) : TC;

      int count4 = nsteps * BATCH * HID / 4;
      int cblocks = (count4 + 255) / 256; if (cblocks > 2048) cblocks = 2048;
      k_cast4<<<cblocks, 256, 0, stream>>>(
          (const float4*)(prev + (size_t)t0 * BATCH * HID), prevb, count4);

      k_gemm_t<<<dim3(NB, nsteps), 256, 0, stream>>>(prevb, WihT,
                                                     bih + (size_t)l * GSZ, tin, HID, GSZ);

      bool last = (t0 + nsteps == LSEQ);
      const ushort* WhhT_p = (const ushort*)(ws + o_WhhT[l]);
      const float* bhh_p = bhh + (size_t)l * GSZ;
      const ushort* tin_p = tin;
      ushort* h0_p = hb0;
      ushort* h1_p = hb1;
      float* c_p = cst;
      float* ohs  = out + OFF_OUTS + ((size_t)l * LSEQ + t0) * BATCH * HID;
      float* ohs2 = (l == 1) ? (out + OFF_OUTPUT + (size_t)t0 * BATCH * HID) : nullptr;
      float* dfsp  = out + OFF_DFS  + ((size_t)l * LSEQ + t0) * BATCH;
      float* dinsp = out + OFF_DINS + ((size_t)l * LSEQ + t0) * BATCH;
      float* hTp = last ? (out + OFF_HT + (size_t)l * BATCH * HID) : nullptr;
      float* cTp = last ? (out + OFF_CT + (size_t)l * BATCH * HID) : nullptr;
      int nsteps_v = nsteps;
      int barbase_v = barbase;

      void* args[] = {&WhhT_p, &bhh_p, &tin_p, &h0_p, &h1_p, &c_p, &ohs, &ohs2,
                      &dfsp, &dinsp, &hTp, &cTp, &barmem, &nsteps_v, &barbase_v};
      hipLaunchCooperativeKernel((const void*)k_scan, dim3(NBLK), dim3(1024),
                                 args, 0, stream);
      barbase += nsteps - 1;

      // h parity: if nsteps is odd the final h landed in the "other" buffer
      if (nsteps & 1) { ushort* tmp = hb0; hb0 = hb1; hb1 = tmp; }
    }
  }
}